// Round 6
// baseline (681.893 us; speedup 1.0000x reference)
//
#include <hip/hip_runtime.h>
#include <hip/hip_bf16.h>

#define NN 50000
#define NE 800000

typedef __bf16 bf16_t;
typedef bf16_t bf16x4 __attribute__((ext_vector_type(4)));
typedef bf16_t bf16x8 __attribute__((ext_vector_type(8)));
typedef float f32x4 __attribute__((ext_vector_type(4)));

// 8-element MFMA A/B fragment: {p[0..3], p[16..19]} (two k-halves of 16x16x32).
__device__ __forceinline__ bf16x8 load_frag(const bf16_t* p) {
    bf16x4 lo = *(const bf16x4*)p;
    bf16x4 hi = *(const bf16x4*)(p + 16);
    bf16x8 f;
    f[0] = lo[0]; f[1] = lo[1]; f[2] = lo[2]; f[3] = lo[3];
    f[4] = hi[0]; f[5] = hi[1]; f[6] = hi[2]; f[7] = hi[3];
    return f;
}

// ---------------- input projection: h = x @ in_w + in_b (bf16) ----------------
__global__ void k_input(const float* __restrict__ x, const float* __restrict__ w,
                        const float* __restrict__ b, bf16_t* __restrict__ h) {
    int gid = blockIdx.x * blockDim.x + threadIdx.x;
    if (gid >= NN * 64) return;
    int n = gid >> 6, j = gid & 63;
    float a = b[j];
    a += x[n * 3 + 0] * w[0 * 64 + j];
    a += x[n * 3 + 1] * w[1 * 64 + j];
    a += x[n * 3 + 2] * w[2 * 64 + j];
    h[gid] = (bf16_t)a;
}

// ---------------- weight prep ----------------
__global__ void k_prep(const float* __restrict__ mw1, const float* __restrict__ uw1,
                       const float* __restrict__ uw2,
                       bf16_t* __restrict__ w1t, bf16_t* __restrict__ u1t,
                       bf16_t* __restrict__ u2t) {
    int gid = blockIdx.x * blockDim.x + threadIdx.x;
    if (gid < 3 * 64 * 128) {
        int l = gid / 8192, r = gid % 8192, hid = r >> 7, k = r & 127;
        w1t[gid] = (bf16_t)mw1[l * 8192 + k * 64 + hid];
    }
    if (gid < 3 * 64 * 64) {
        int l = gid / 4096, r = gid % 4096, hid = r >> 6, k = r & 63;
        u1t[gid] = (bf16_t)uw1[l * 8192 + k * 64 + hid];
        u2t[gid] = (bf16_t)uw2[l * 4096 + k * 64 + hid];
    }
}

// W2''^T[l][hid][k] = sum_j msg_w2[l][k][j] * upd_w1[l][64+j][hid]  (bf16)
// cvec[l][hid]     = sum_j msg_b2[l][j]    * upd_w1[l][64+j][hid]  (f32)
__global__ void k_prep2(const float* __restrict__ mw2, const float* __restrict__ mb2,
                        const float* __restrict__ uw1,
                        bf16_t* __restrict__ w2u, float* __restrict__ cvec) {
    int gid = blockIdx.x * blockDim.x + threadIdx.x;
    if (gid < 3 * 64 * 64) {
        int l = gid / 4096, r = gid % 4096, hid = r >> 6, k = r & 63;
        float s = 0.f;
        for (int j = 0; j < 64; ++j)
            s += mw2[l * 4096 + k * 64 + j] * uw1[l * 8192 + (64 + j) * 64 + hid];
        w2u[l * 4096 + hid * 64 + k] = (bf16_t)s;
    }
    if (gid < 3 * 64) {
        int l = gid / 64, hid = gid % 64;
        float s = 0.f;
        for (int j = 0; j < 64; ++j)
            s += mb2[l * 64 + j] * uw1[l * 8192 + (64 + j) * 64 + hid];
        cvec[gid] = s;
    }
}

// out_w split: whi[j][k] = bf16(out_w[k][j]); wlo[j][k] = bf16(out_w[k][j] - whi)
__global__ void k_prep3(const float* __restrict__ ow,
                        bf16_t* __restrict__ whi, bf16_t* __restrict__ wlo) {
    int gid = blockIdx.x * blockDim.x + threadIdx.x;
    if (gid >= 128 * 64) return;
    int j = gid >> 6, k = gid & 63;
    float w = ow[k * 128 + j];
    bf16_t hi = (bf16_t)w;
    whi[gid] = hi;
    wlo[gid] = (bf16_t)(w - (float)hi);
}

// ---------------- counting sort of edges by destination ----------------
__global__ void k_hist(const int* __restrict__ ei, int* __restrict__ deg) {
    int gid = blockIdx.x * blockDim.x + threadIdx.x;
    if (gid < NE) atomicAdd(&deg[ei[NE + gid]], 1);
}

#define SCAN_BLKS 196
__global__ void k_scan1(const int* __restrict__ deg, int* __restrict__ tscan,
                        int* __restrict__ part) {
    __shared__ int lds[256];
    int tid = threadIdx.x;
    int gid = blockIdx.x * 256 + tid;
    int v = (gid < NN) ? deg[gid] : 0;
    lds[tid] = v;
    __syncthreads();
    for (int off = 1; off < 256; off <<= 1) {
        int t = (tid >= off) ? lds[tid - off] : 0;
        __syncthreads();
        lds[tid] += t;
        __syncthreads();
    }
    if (gid < NN) tscan[gid] = lds[tid] - v;
    if (tid == 255) part[blockIdx.x] = lds[255];
}

__global__ void k_scan2(const int* __restrict__ part, int* __restrict__ pscan) {
    __shared__ int lds[256];
    int tid = threadIdx.x;
    int v = (tid < SCAN_BLKS) ? part[tid] : 0;
    lds[tid] = v;
    __syncthreads();
    for (int off = 1; off < 256; off <<= 1) {
        int t = (tid >= off) ? lds[tid - off] : 0;
        __syncthreads();
        lds[tid] += t;
        __syncthreads();
    }
    pscan[tid] = lds[tid] - v;
}

__global__ void k_scan3(const int* __restrict__ tscan, const int* __restrict__ pscan,
                        int* __restrict__ offs, int* __restrict__ cursor) {
    int gid = blockIdx.x * blockDim.x + threadIdx.x;
    if (gid < NN) {
        int o = tscan[gid] + pscan[gid >> 8];
        offs[gid] = o;
        cursor[gid] = o;
    }
    if (gid == 0) offs[NN] = NE;
}

__global__ void k_scatter(const int* __restrict__ ei, int* __restrict__ cursor,
                          int* __restrict__ ssrc) {
    int gid = blockIdx.x * blockDim.x + threadIdx.x;
    if (gid < NE) {
        int c = ei[NE + gid];
        int pos = atomicAdd(&cursor[c], 1);
        ssrc[pos] = ei[gid];
    }
}

// ---------------- degree-balanced node order (counting sort over degree) ----------------
// nodeorder[] = node ids sorted by degree (bins clamped to 63) so the 8 nodes
// sharing a wave in k_edge have near-equal edge counts (kills the max-of-8
// divergence tax, ~1.6x at Poisson(16)).
__global__ void k_dhist(const int* __restrict__ deg, int* __restrict__ dbins) {
    int gid = blockIdx.x * blockDim.x + threadIdx.x;
    if (gid < NN) {
        int b = deg[gid]; b = b > 63 ? 63 : b;
        atomicAdd(&dbins[b], 1);
    }
}

__global__ void k_dscan(const int* __restrict__ dbins, int* __restrict__ dcur) {
    __shared__ int lds[64];
    int tid = threadIdx.x;
    if (tid < 64) lds[tid] = dbins[tid];
    __syncthreads();
    if (tid == 0) {
        int a = 0;
        for (int i = 0; i < 64; ++i) { int t = lds[i]; lds[i] = a; a += t; }
    }
    __syncthreads();
    if (tid < 64) dcur[tid] = lds[tid];
}

__global__ void k_dscatter(const int* __restrict__ deg, int* __restrict__ dcur,
                           int* __restrict__ nodeorder) {
    int gid = blockIdx.x * blockDim.x + threadIdx.x;
    if (gid < NN) {
        int b = deg[gid]; b = b > 63 ? 63 : b;
        int pos = atomicAdd(&dcur[b], 1);
        nodeorder[pos] = gid;
    }
}

// ---------------- per-layer: P = h@W1top, Q = h@W1bot + b1 (MFMA, swapped) ----------------
__global__ void k_pq(const bf16_t* __restrict__ h, const bf16_t* __restrict__ w1t,
                     const float* __restrict__ b1,
                     bf16_t* __restrict__ P, bf16_t* __restrict__ Q) {
    const int lane = threadIdx.x & 63;
    const int g = lane >> 4;
    const int m16 = lane & 15;
    const int wid = (blockIdx.x * blockDim.x + threadIdx.x) >> 6;
    const int nw = (gridDim.x * blockDim.x) >> 6;

    bf16x8 wtop[2][4], wbot[2][4];
    #pragma unroll
    for (int s = 0; s < 2; ++s)
        #pragma unroll
        for (int nt = 0; nt < 4; ++nt) {
            wtop[s][nt] = load_frag(w1t + (16 * nt + m16) * 128 + 32 * s + 4 * g);
            wbot[s][nt] = load_frag(w1t + (16 * nt + m16) * 128 + 64 + 32 * s + 4 * g);
        }
    float b1f[4][4];
    #pragma unroll
    for (int nt = 0; nt < 4; ++nt)
        #pragma unroll
        for (int r = 0; r < 4; ++r) b1f[nt][r] = b1[16 * nt + 4 * g + r];

    const int ntiles = NN / 16;
    for (int t = wid; t < ntiles; t += nw) {
        const int node = t * 16 + m16;
        const bf16_t* hp = h + node * 64 + 4 * g;
        bf16x8 hfr[2];
        hfr[0] = load_frag(hp);
        hfr[1] = load_frag(hp + 32);

        f32x4 accP[4], accQ[4];
        #pragma unroll
        for (int nt = 0; nt < 4; ++nt) {
            accP[nt] = (f32x4){0.f, 0.f, 0.f, 0.f};
            accQ[nt] = (f32x4){0.f, 0.f, 0.f, 0.f};
        }
        #pragma unroll
        for (int s = 0; s < 2; ++s)
            #pragma unroll
            for (int nt = 0; nt < 4; ++nt) {
                accP[nt] = __builtin_amdgcn_mfma_f32_16x16x32_bf16(wtop[s][nt], hfr[s], accP[nt], 0, 0, 0);
                accQ[nt] = __builtin_amdgcn_mfma_f32_16x16x32_bf16(wbot[s][nt], hfr[s], accQ[nt], 0, 0, 0);
            }
        #pragma unroll
        for (int nt = 0; nt < 4; ++nt) {
            bf16x4 vp, vq;
            #pragma unroll
            for (int r = 0; r < 4; ++r) {
                vp[r] = (bf16_t)accP[nt][r];
                vq[r] = (bf16_t)(accQ[nt][r] + b1f[nt][r]);
            }
            *(bf16x4*)(P + node * 64 + 16 * nt + 4 * g) = vp;
            *(bf16x4*)(Q + node * 64 + 16 * nt + 4 * g) = vq;
        }
    }
}

// ---------------- per-layer edge phase: S[n] = sum_{e->n} relu(P[src_e] + Q[n]) ----------------
// thread = (node-slot, feature-octet); node ids come from degree-sorted
// nodeorder so all 8 nodes in a wave have near-equal degree.
__global__ void k_edge(const bf16_t* __restrict__ P, const bf16_t* __restrict__ Q,
                       const int* __restrict__ ssrc, const int* __restrict__ offs,
                       const int* __restrict__ nodeorder, bf16_t* __restrict__ S) {
    int gid = blockIdx.x * blockDim.x + threadIdx.x;
    int slot = gid >> 3, f8 = gid & 7;
    if (slot >= NN) return;
    int node = nodeorder[slot];
    bf16x8 qv = *(const bf16x8*)(Q + node * 64 + f8 * 8);
    float qf[8], a[8];
    #pragma unroll
    for (int r = 0; r < 8; ++r) { qf[r] = (float)qv[r]; a[r] = 0.f; }
    const int beg = offs[node], end = offs[node + 1];
    int p = beg;
    const int n4 = beg + ((end - beg) & ~3);
    for (; p < n4; p += 4) {
        int s0 = ssrc[p], s1 = ssrc[p + 1], s2 = ssrc[p + 2], s3 = ssrc[p + 3];
        bf16x8 v0 = *(const bf16x8*)(P + s0 * 64 + f8 * 8);
        bf16x8 v1 = *(const bf16x8*)(P + s1 * 64 + f8 * 8);
        bf16x8 v2 = *(const bf16x8*)(P + s2 * 64 + f8 * 8);
        bf16x8 v3 = *(const bf16x8*)(P + s3 * 64 + f8 * 8);
        #pragma unroll
        for (int r = 0; r < 8; ++r) {
            float x0 = (float)v0[r] + qf[r];
            float x1 = (float)v1[r] + qf[r];
            float x2 = (float)v2[r] + qf[r];
            float x3 = (float)v3[r] + qf[r];
            a[r] += (x0 > 0.f ? x0 : 0.f) + (x1 > 0.f ? x1 : 0.f)
                  + (x2 > 0.f ? x2 : 0.f) + (x3 > 0.f ? x3 : 0.f);
        }
    }
    for (; p < end; ++p) {
        int s = ssrc[p];
        bf16x8 v = *(const bf16x8*)(P + s * 64 + f8 * 8);
        #pragma unroll
        for (int r = 0; r < 8; ++r) {
            float x = (float)v[r] + qf[r];
            a[r] += x > 0.f ? x : 0.f;
        }
    }
    bf16x8 sv;
    #pragma unroll
    for (int r = 0; r < 8; ++r) sv[r] = (bf16_t)a[r];
    *(bf16x8*)(S + node * 64 + f8 * 8) = sv;
}

// ---------------- per-layer fused update ----------------
// pre1 = h@U1top + S@W2'' + deg*c + ub1; h_new = relu(relu(pre1)@U2 + ub2)
__global__ void k_upd(const bf16_t* __restrict__ h, const bf16_t* __restrict__ S,
                      const int* __restrict__ deg,
                      const bf16_t* __restrict__ u1t, const bf16_t* __restrict__ w2u,
                      const bf16_t* __restrict__ u2t,
                      const float* __restrict__ ub1, const float* __restrict__ cvec,
                      const float* __restrict__ ub2, bf16_t* __restrict__ hn) {
    const int lane = threadIdx.x & 63;
    const int g = lane >> 4;
    const int m16 = lane & 15;
    const int wid = (blockIdx.x * blockDim.x + threadIdx.x) >> 6;
    const int nw = (gridDim.x * blockDim.x) >> 6;

    bf16x8 u1f[2][4], w2f[2][4], u2f[2][4];
    #pragma unroll
    for (int s = 0; s < 2; ++s)
        #pragma unroll
        for (int nt = 0; nt < 4; ++nt) {
            u1f[s][nt] = load_frag(u1t + (16 * nt + m16) * 64 + 32 * s + 4 * g);
            w2f[s][nt] = load_frag(w2u + (16 * nt + m16) * 64 + 32 * s + 4 * g);
            u2f[s][nt] = load_frag(u2t + (16 * nt + m16) * 64 + 32 * s + 4 * g);
        }
    float b1f[4][4], cf[4][4], b2f[4][4];
    #pragma unroll
    for (int nt = 0; nt < 4; ++nt)
        #pragma unroll
        for (int r = 0; r < 4; ++r) {
            b1f[nt][r] = ub1[16 * nt + 4 * g + r];
            cf[nt][r] = cvec[16 * nt + 4 * g + r];
            b2f[nt][r] = ub2[16 * nt + 4 * g + r];
        }

    const int ntiles = NN / 16;
    for (int t = wid; t < ntiles; t += nw) {
        const int node = t * 16 + m16;
        bf16x8 hfr[2], sfr[2];
        hfr[0] = load_frag(h + node * 64 + 4 * g);
        hfr[1] = load_frag(h + node * 64 + 4 * g + 32);
        sfr[0] = load_frag(S + node * 64 + 4 * g);
        sfr[1] = load_frag(S + node * 64 + 4 * g + 32);
        float dv = (float)deg[node];

        f32x4 acc1[4];
        #pragma unroll
        for (int nt = 0; nt < 4; ++nt) acc1[nt] = (f32x4){0.f, 0.f, 0.f, 0.f};
        #pragma unroll
        for (int s = 0; s < 2; ++s)
            #pragma unroll
            for (int nt = 0; nt < 4; ++nt) {
                acc1[nt] = __builtin_amdgcn_mfma_f32_16x16x32_bf16(u1f[s][nt], hfr[s], acc1[nt], 0, 0, 0);
                acc1[nt] = __builtin_amdgcn_mfma_f32_16x16x32_bf16(w2f[s][nt], sfr[s], acc1[nt], 0, 0, 0);
            }

        bf16x8 hb[2];
        #pragma unroll
        for (int s = 0; s < 2; ++s) {
            bf16x8 f;
            #pragma unroll
            for (int half = 0; half < 2; ++half) {
                const int nt = 2 * s + half;
                #pragma unroll
                for (int r = 0; r < 4; ++r) {
                    float v = acc1[nt][r] + b1f[nt][r] + dv * cf[nt][r];
                    v = v > 0.f ? v : 0.f;
                    f[4 * half + r] = (bf16_t)v;
                }
            }
            hb[s] = f;
        }

        f32x4 acc2[4];
        #pragma unroll
        for (int nt = 0; nt < 4; ++nt) acc2[nt] = (f32x4){0.f, 0.f, 0.f, 0.f};
        #pragma unroll
        for (int s = 0; s < 2; ++s)
            #pragma unroll
            for (int nt = 0; nt < 4; ++nt)
                acc2[nt] = __builtin_amdgcn_mfma_f32_16x16x32_bf16(u2f[s][nt], hb[s], acc2[nt], 0, 0, 0);

        #pragma unroll
        for (int nt = 0; nt < 4; ++nt) {
            bf16x4 v4;
            #pragma unroll
            for (int r = 0; r < 4; ++r) {
                float v = acc2[nt][r] + b2f[nt][r];
                v4[r] = (bf16_t)(v > 0.f ? v : 0.f);
            }
            *(bf16x4*)(hn + node * 64 + 16 * nt + 4 * g) = v4;
        }
    }
}

// ---------------- output projection (MFMA, split hi/lo weights) ----------------
__global__ __launch_bounds__(256)
void k_outm(const bf16_t* __restrict__ whi_t, const bf16_t* __restrict__ wlo_t,
            const bf16_t* __restrict__ h, const float* __restrict__ b,
            float* __restrict__ out) {
    const int lane = threadIdx.x & 63;
    const int g = lane >> 4;
    const int m16 = lane & 15;
    const int wid = (blockIdx.x * blockDim.x + threadIdx.x) >> 6;
    const int nw = (gridDim.x * blockDim.x) >> 6;

    bf16x8 whi[2][8], wlo[2][8];
    #pragma unroll
    for (int s = 0; s < 2; ++s)
        #pragma unroll
        for (int nt = 0; nt < 8; ++nt) {
            whi[s][nt] = load_frag(whi_t + (16 * nt + m16) * 64 + 32 * s + 4 * g);
            wlo[s][nt] = load_frag(wlo_t + (16 * nt + m16) * 64 + 32 * s + 4 * g);
        }
    f32x4 bfv[8];
    #pragma unroll
    for (int nt = 0; nt < 8; ++nt)
        #pragma unroll
        for (int r = 0; r < 4; ++r) bfv[nt][r] = b[16 * nt + 4 * g + r];

    const int ntiles = NN / 16;
    for (int t = wid; t < ntiles; t += nw) {
        const int node = t * 16 + m16;
        bf16x8 hfr[2];
        hfr[0] = load_frag(h + node * 64 + 4 * g);
        hfr[1] = load_frag(h + node * 64 + 4 * g + 32);

        f32x4 acc[8];
        #pragma unroll
        for (int nt = 0; nt < 8; ++nt) acc[nt] = (f32x4){0.f, 0.f, 0.f, 0.f};
        #pragma unroll
        for (int s = 0; s < 2; ++s)
            #pragma unroll
            for (int nt = 0; nt < 8; ++nt) {
                acc[nt] = __builtin_amdgcn_mfma_f32_16x16x32_bf16(whi[s][nt], hfr[s], acc[nt], 0, 0, 0);
                acc[nt] = __builtin_amdgcn_mfma_f32_16x16x32_bf16(wlo[s][nt], hfr[s], acc[nt], 0, 0, 0);
            }
        #pragma unroll
        for (int nt = 0; nt < 8; ++nt)
            *(f32x4*)(out + node * 128 + 16 * nt + 4 * g) = acc[nt] + bfv[nt];
    }
}

extern "C" void kernel_launch(void* const* d_in, const int* in_sizes, int n_in,
                              void* d_out, int out_size, void* d_ws, size_t ws_size,
                              hipStream_t stream) {
    const float* x      = (const float*)d_in[0];
    const int*   ei     = (const int*)d_in[1];
    const float* in_w   = (const float*)d_in[2];
    const float* in_b   = (const float*)d_in[3];
    const float* msg_w1 = (const float*)d_in[4];
    const float* msg_b1 = (const float*)d_in[5];
    const float* msg_w2 = (const float*)d_in[6];
    const float* msg_b2 = (const float*)d_in[7];
    const float* upd_w1 = (const float*)d_in[8];
    const float* upd_b1 = (const float*)d_in[9];
    const float* upd_w2 = (const float*)d_in[10];
    const float* upd_b2 = (const float*)d_in[11];
    const float* out_w  = (const float*)d_in[12];
    const float* out_b  = (const float*)d_in[13];
    float* out = (float*)d_out;

    char* ws = (char*)d_ws;
    bf16_t* h_a    = (bf16_t*)(ws);
    bf16_t* h_b    = (bf16_t*)(ws + 6400000);
    bf16_t* P      = (bf16_t*)(ws + 12800000);
    bf16_t* Q      = (bf16_t*)(ws + 19200000);
    bf16_t* S      = (bf16_t*)(ws + 25600000);
    int*    ssrc   = (int*)   (ws + 32000000);
    int*    deg    = (int*)   (ws + 35200000);
    int*    offs   = (int*)   (ws + 35400000);
    int*    cursor = (int*)   (ws + 35600128);
    int*    tscan  = (int*)   (ws + 35800192);
    int*    part   = (int*)   (ws + 36000256);
    int*    pscan  = (int*)   (ws + 36001280);
    bf16_t* w1t    = (bf16_t*)(ws + 36002304);
    bf16_t* u1t    = (bf16_t*)(ws + 36051456);
    bf16_t* u2t    = (bf16_t*)(ws + 36076032);
    bf16_t* w2u    = (bf16_t*)(ws + 36100608);
    float*  cvec   = (float*) (ws + 36125184);
    bf16_t* whi    = (bf16_t*)(ws + 36126208);   // 16 KB
    bf16_t* wlo    = (bf16_t*)(ws + 36142592);   // 16 KB
    int*    nodeorder = (int*)(ws + 36158976);   // 200 KB
    int*    dbins  = (int*)   (ws + 36359040);   // 256 B
    int*    dcur   = (int*)   (ws + 36359296);   // 256 B

    // weight prep + input projection
    k_prep<<<96, 256, 0, stream>>>(msg_w1, upd_w1, upd_w2, w1t, u1t, u2t);
    k_prep2<<<48, 256, 0, stream>>>(msg_w2, msg_b2, upd_w1, w2u, cvec);
    k_prep3<<<32, 256, 0, stream>>>(out_w, whi, wlo);
    k_input<<<(NN * 64 + 255) / 256, 256, 0, stream>>>(x, in_w, in_b, h_a);

    // counting sort of edges by destination
    hipMemsetAsync(deg, 0, NN * sizeof(int), stream);
    hipMemsetAsync(dbins, 0, 64 * sizeof(int), stream);
    k_hist<<<(NE + 255) / 256, 256, 0, stream>>>(ei, deg);
    // degree-balanced node order (needs deg)
    k_dhist<<<SCAN_BLKS, 256, 0, stream>>>(deg, dbins);
    k_dscan<<<1, 64, 0, stream>>>(dbins, dcur);
    k_dscatter<<<SCAN_BLKS, 256, 0, stream>>>(deg, dcur, nodeorder);
    // per-node edge offsets + scatter
    k_scan1<<<SCAN_BLKS, 256, 0, stream>>>(deg, tscan, part);
    k_scan2<<<1, 256, 0, stream>>>(part, pscan);
    k_scan3<<<SCAN_BLKS, 256, 0, stream>>>(tscan, pscan, offs, cursor);
    k_scatter<<<(NE + 255) / 256, 256, 0, stream>>>(ei, cursor, ssrc);

    bf16_t* hc = h_a;
    bf16_t* hn = h_b;
    for (int l = 0; l < 3; ++l) {
        k_pq<<<512, 256, 0, stream>>>(hc, w1t + l * 8192, msg_b1 + l * 64, P, Q);
        k_edge<<<(NN * 8 + 255) / 256, 256, 0, stream>>>(P, Q, ssrc, offs, nodeorder, S);
        k_upd<<<512, 256, 0, stream>>>(hc, S, deg, u1t + l * 4096, w2u + l * 4096,
                                       u2t + l * 4096, upd_b1 + l * 64, cvec + l * 64,
                                       upd_b2 + l * 64, hn);
        bf16_t* tmp = hc; hc = hn; hn = tmp;
    }
    k_outm<<<640, 256, 0, stream>>>(whi, wlo, hc, out_b, out);
}

// Round 7
// 389.213 us; speedup vs baseline: 1.7520x; 1.7520x over previous
//
#include <hip/hip_runtime.h>
#include <hip/hip_bf16.h>

#define NN 50000
#define NE 800000

typedef __bf16 bf16_t;
typedef bf16_t bf16x4 __attribute__((ext_vector_type(4)));
typedef bf16_t bf16x8 __attribute__((ext_vector_type(8)));
typedef float f32x4 __attribute__((ext_vector_type(4)));

// 8-element MFMA A/B fragment: {p[0..3], p[16..19]} (two k-halves of 16x16x32).
__device__ __forceinline__ bf16x8 load_frag(const bf16_t* p) {
    bf16x4 lo = *(const bf16x4*)p;
    bf16x4 hi = *(const bf16x4*)(p + 16);
    bf16x8 f;
    f[0] = lo[0]; f[1] = lo[1]; f[2] = lo[2]; f[3] = lo[3];
    f[4] = hi[0]; f[5] = hi[1]; f[6] = hi[2]; f[7] = hi[3];
    return f;
}

// ---------------- weight prep ----------------
__global__ void k_prep(const float* __restrict__ mw1, const float* __restrict__ uw1,
                       const float* __restrict__ uw2,
                       bf16_t* __restrict__ w1t, bf16_t* __restrict__ u1t,
                       bf16_t* __restrict__ u2t) {
    int gid = blockIdx.x * blockDim.x + threadIdx.x;
    if (gid < 3 * 64 * 128) {
        int l = gid / 8192, r = gid % 8192, hid = r >> 7, k = r & 127;
        w1t[gid] = (bf16_t)mw1[l * 8192 + k * 64 + hid];
    }
    if (gid < 3 * 64 * 64) {
        int l = gid / 4096, r = gid % 4096, hid = r >> 6, k = r & 63;
        u1t[gid] = (bf16_t)uw1[l * 8192 + k * 64 + hid];
        u2t[gid] = (bf16_t)uw2[l * 4096 + k * 64 + hid];
    }
}

// W2''^T[l][hid][k] = sum_j msg_w2[l][k][j] * upd_w1[l][64+j][hid]  (bf16)
// cvec[l][hid]     = sum_j msg_b2[l][j]    * upd_w1[l][64+j][hid]  (f32)
__global__ void k_prep2(const float* __restrict__ mw2, const float* __restrict__ mb2,
                        const float* __restrict__ uw1,
                        bf16_t* __restrict__ w2u, float* __restrict__ cvec) {
    int gid = blockIdx.x * blockDim.x + threadIdx.x;
    if (gid < 3 * 64 * 64) {
        int l = gid / 4096, r = gid % 4096, hid = r >> 6, k = r & 63;
        float s = 0.f;
        for (int j = 0; j < 64; ++j)
            s += mw2[l * 4096 + k * 64 + j] * uw1[l * 8192 + (64 + j) * 64 + hid];
        w2u[l * 4096 + hid * 64 + k] = (bf16_t)s;
    }
    if (gid < 3 * 64) {
        int l = gid / 64, hid = gid % 64;
        float s = 0.f;
        for (int j = 0; j < 64; ++j)
            s += mb2[l * 64 + j] * uw1[l * 8192 + (64 + j) * 64 + hid];
        cvec[gid] = s;
    }
}

// out_w split: whi[j][k] = bf16(out_w[k][j]); wlo[j][k] = bf16(out_w[k][j] - whi)
__global__ void k_prep3(const float* __restrict__ ow,
                        bf16_t* __restrict__ whi, bf16_t* __restrict__ wlo) {
    int gid = blockIdx.x * blockDim.x + threadIdx.x;
    if (gid >= 128 * 64) return;
    int j = gid >> 6, k = gid & 63;
    float w = ow[k * 128 + j];
    bf16_t hi = (bf16_t)w;
    whi[gid] = hi;
    wlo[gid] = (bf16_t)(w - (float)hi);
}

// ---------------- counting sort of edges by destination ----------------
__global__ void k_hist(const int* __restrict__ ei, int* __restrict__ deg) {
    int gid = blockIdx.x * blockDim.x + threadIdx.x;
    if (gid < NE) atomicAdd(&deg[ei[NE + gid]], 1);
}

#define SCAN_BLKS 196
__global__ void k_scan1(const int* __restrict__ deg, int* __restrict__ tscan,
                        int* __restrict__ part) {
    __shared__ int lds[256];
    int tid = threadIdx.x;
    int gid = blockIdx.x * 256 + tid;
    int v = (gid < NN) ? deg[gid] : 0;
    lds[tid] = v;
    __syncthreads();
    for (int off = 1; off < 256; off <<= 1) {
        int t = (tid >= off) ? lds[tid - off] : 0;
        __syncthreads();
        lds[tid] += t;
        __syncthreads();
    }
    if (gid < NN) tscan[gid] = lds[tid] - v;
    if (tid == 255) part[blockIdx.x] = lds[255];
}

__global__ void k_scan2(const int* __restrict__ part, int* __restrict__ pscan) {
    __shared__ int lds[256];
    int tid = threadIdx.x;
    int v = (tid < SCAN_BLKS) ? part[tid] : 0;
    lds[tid] = v;
    __syncthreads();
    for (int off = 1; off < 256; off <<= 1) {
        int t = (tid >= off) ? lds[tid - off] : 0;
        __syncthreads();
        lds[tid] += t;
        __syncthreads();
    }
    pscan[tid] = lds[tid] - v;
}

__global__ void k_scan3(const int* __restrict__ tscan, const int* __restrict__ pscan,
                        int* __restrict__ offs, int* __restrict__ cursor) {
    int gid = blockIdx.x * blockDim.x + threadIdx.x;
    if (gid < NN) {
        int o = tscan[gid] + pscan[gid >> 8];
        offs[gid] = o;
        cursor[gid] = o;
    }
    if (gid == 0) offs[NN] = NE;
}

__global__ void k_scatter(const int* __restrict__ ei, int* __restrict__ cursor,
                          int* __restrict__ ssrc) {
    int gid = blockIdx.x * blockDim.x + threadIdx.x;
    if (gid < NE) {
        int c = ei[NE + gid];
        int pos = atomicAdd(&cursor[c], 1);
        ssrc[pos] = ei[gid];
    }
}

// ---------------- fused input projection + layer-0 P/Q ----------------
// h0 computed per-lane directly in B-fragment layout (f = 32s+4g+j / +16),
// written to global, then P0/Q0 via MFMA — no separate k_input pass.
__global__ __launch_bounds__(256)
void k_inputpq(const float* __restrict__ x, const float* __restrict__ iw,
               const float* __restrict__ ib,
               const bf16_t* __restrict__ w1t, const float* __restrict__ b1,
               bf16_t* __restrict__ h, bf16_t* __restrict__ P, bf16_t* __restrict__ Q) {
    const int lane = threadIdx.x & 63;
    const int g = lane >> 4;
    const int m16 = lane & 15;
    const int wid = (blockIdx.x * blockDim.x + threadIdx.x) >> 6;
    const int nw = (gridDim.x * blockDim.x) >> 6;

    bf16x8 wtop[2][4], wbot[2][4];
    #pragma unroll
    for (int s = 0; s < 2; ++s)
        #pragma unroll
        for (int nt = 0; nt < 4; ++nt) {
            wtop[s][nt] = load_frag(w1t + (16 * nt + m16) * 128 + 32 * s + 4 * g);
            wbot[s][nt] = load_frag(w1t + (16 * nt + m16) * 128 + 64 + 32 * s + 4 * g);
        }
    float b1f[4][4];
    #pragma unroll
    for (int nt = 0; nt < 4; ++nt)
        #pragma unroll
        for (int r = 0; r < 4; ++r) b1f[nt][r] = b1[16 * nt + 4 * g + r];

    // in_w columns / bias for this lane's 16 fragment features
    float wcol[3][2][8], bcol[2][8];
    #pragma unroll
    for (int s = 0; s < 2; ++s)
        #pragma unroll
        for (int j = 0; j < 8; ++j) {
            int f = 32 * s + 4 * g + (j < 4 ? j : 16 + j - 4);
            bcol[s][j] = ib[f];
            #pragma unroll
            for (int i = 0; i < 3; ++i) wcol[i][s][j] = iw[i * 64 + f];
        }

    const int ntiles = NN / 16;
    for (int t = wid; t < ntiles; t += nw) {
        const int node = t * 16 + m16;
        float x0 = x[node * 3 + 0], x1 = x[node * 3 + 1], x2 = x[node * 3 + 2];
        bf16x8 hb[2];
        #pragma unroll
        for (int s = 0; s < 2; ++s)
            #pragma unroll
            for (int j = 0; j < 8; ++j) {
                float hf = bcol[s][j] + x0 * wcol[0][s][j] + x1 * wcol[1][s][j]
                         + x2 * wcol[2][s][j];
                hb[s][j] = (bf16_t)hf;
            }
        #pragma unroll
        for (int s = 0; s < 2; ++s) {
            bf16x4 lo, hi;
            #pragma unroll
            for (int j = 0; j < 4; ++j) { lo[j] = hb[s][j]; hi[j] = hb[s][4 + j]; }
            *(bf16x4*)(h + node * 64 + 32 * s + 4 * g) = lo;
            *(bf16x4*)(h + node * 64 + 32 * s + 16 + 4 * g) = hi;
        }

        f32x4 accP[4], accQ[4];
        #pragma unroll
        for (int nt = 0; nt < 4; ++nt) {
            accP[nt] = (f32x4){0.f, 0.f, 0.f, 0.f};
            accQ[nt] = (f32x4){0.f, 0.f, 0.f, 0.f};
        }
        #pragma unroll
        for (int s = 0; s < 2; ++s)
            #pragma unroll
            for (int nt = 0; nt < 4; ++nt) {
                accP[nt] = __builtin_amdgcn_mfma_f32_16x16x32_bf16(wtop[s][nt], hb[s], accP[nt], 0, 0, 0);
                accQ[nt] = __builtin_amdgcn_mfma_f32_16x16x32_bf16(wbot[s][nt], hb[s], accQ[nt], 0, 0, 0);
            }
        #pragma unroll
        for (int nt = 0; nt < 4; ++nt) {
            bf16x4 vp, vq;
            #pragma unroll
            for (int r = 0; r < 4; ++r) {
                vp[r] = (bf16_t)accP[nt][r];
                vq[r] = (bf16_t)(accQ[nt][r] + b1f[nt][r]);
            }
            *(bf16x4*)(P + node * 64 + 16 * nt + 4 * g) = vp;
            *(bf16x4*)(Q + node * 64 + 16 * nt + 4 * g) = vq;
        }
    }
}

// ---------------- per-layer edge phase: S[n] = sum_{e->n} relu(P[src_e] + Q[n]) ----------------
// thread = (node, feature-octet): 8 lanes/node, 8 nodes/wave -> 8 independent
// edge streams per wave; unroll x4 -> up to 32 outstanding gathers.
__global__ void k_edge(const bf16_t* __restrict__ P, const bf16_t* __restrict__ Q,
                       const int* __restrict__ ssrc, const int* __restrict__ offs,
                       bf16_t* __restrict__ S) {
    int gid = blockIdx.x * blockDim.x + threadIdx.x;
    int node = gid >> 3, f8 = gid & 7;
    if (node >= NN) return;
    bf16x8 qv = *(const bf16x8*)(Q + node * 64 + f8 * 8);
    float qf[8], a[8];
    #pragma unroll
    for (int r = 0; r < 8; ++r) { qf[r] = (float)qv[r]; a[r] = 0.f; }
    const int beg = offs[node], end = offs[node + 1];
    int p = beg;
    const int n4 = beg + ((end - beg) & ~3);
    for (; p < n4; p += 4) {
        int s0 = ssrc[p], s1 = ssrc[p + 1], s2 = ssrc[p + 2], s3 = ssrc[p + 3];
        bf16x8 v0 = *(const bf16x8*)(P + s0 * 64 + f8 * 8);
        bf16x8 v1 = *(const bf16x8*)(P + s1 * 64 + f8 * 8);
        bf16x8 v2 = *(const bf16x8*)(P + s2 * 64 + f8 * 8);
        bf16x8 v3 = *(const bf16x8*)(P + s3 * 64 + f8 * 8);
        #pragma unroll
        for (int r = 0; r < 8; ++r) {
            float x0 = (float)v0[r] + qf[r];
            float x1 = (float)v1[r] + qf[r];
            float x2 = (float)v2[r] + qf[r];
            float x3 = (float)v3[r] + qf[r];
            a[r] += (x0 > 0.f ? x0 : 0.f) + (x1 > 0.f ? x1 : 0.f)
                  + (x2 > 0.f ? x2 : 0.f) + (x3 > 0.f ? x3 : 0.f);
        }
    }
    for (; p < end; ++p) {
        int s = ssrc[p];
        bf16x8 v = *(const bf16x8*)(P + s * 64 + f8 * 8);
        #pragma unroll
        for (int r = 0; r < 8; ++r) {
            float x = (float)v[r] + qf[r];
            a[r] += x > 0.f ? x : 0.f;
        }
    }
    bf16x8 sv;
    #pragma unroll
    for (int r = 0; r < 8; ++r) sv[r] = (bf16_t)a[r];
    *(bf16x8*)(S + node * 64 + f8 * 8) = sv;
}

// ---------------- fused update + next-layer P/Q ----------------
// pre1 = h@U1top + S@W2'' + deg*c + ub1; h_new = relu(relu(pre1)@U2 + ub2).
// acc2's C-layout (col=node=m16, feature=16nt+4g+r) IS the B-fragment layout
// (f = 32s+4g+j / 32s+16+4g+(j-4)) at the same lane: nt0->s0.lo, nt1->s0.hi,
// nt2->s1.lo, nt3->s1.hi. So next-layer P/Q MFMAs run on h_new in-register.
__global__ __launch_bounds__(256)
void k_updpq(const bf16_t* __restrict__ h, const bf16_t* __restrict__ S,
             const int* __restrict__ deg,
             const bf16_t* __restrict__ u1t, const bf16_t* __restrict__ w2u,
             const bf16_t* __restrict__ u2t,
             const float* __restrict__ ub1, const float* __restrict__ cvec,
             const float* __restrict__ ub2,
             const bf16_t* __restrict__ w1tn, const float* __restrict__ b1n,
             bf16_t* __restrict__ hn, bf16_t* __restrict__ P, bf16_t* __restrict__ Q) {
    const int lane = threadIdx.x & 63;
    const int g = lane >> 4;
    const int m16 = lane & 15;
    const int wid = (blockIdx.x * blockDim.x + threadIdx.x) >> 6;
    const int nw = (gridDim.x * blockDim.x) >> 6;

    bf16x8 u1f[2][4], w2f[2][4], u2f[2][4], wtop[2][4], wbot[2][4];
    #pragma unroll
    for (int s = 0; s < 2; ++s)
        #pragma unroll
        for (int nt = 0; nt < 4; ++nt) {
            u1f[s][nt] = load_frag(u1t + (16 * nt + m16) * 64 + 32 * s + 4 * g);
            w2f[s][nt] = load_frag(w2u + (16 * nt + m16) * 64 + 32 * s + 4 * g);
            u2f[s][nt] = load_frag(u2t + (16 * nt + m16) * 64 + 32 * s + 4 * g);
            wtop[s][nt] = load_frag(w1tn + (16 * nt + m16) * 128 + 32 * s + 4 * g);
            wbot[s][nt] = load_frag(w1tn + (16 * nt + m16) * 128 + 64 + 32 * s + 4 * g);
        }
    float b1f[4][4], cf[4][4], b2f[4][4], b1nf[4][4];
    #pragma unroll
    for (int nt = 0; nt < 4; ++nt)
        #pragma unroll
        for (int r = 0; r < 4; ++r) {
            b1f[nt][r] = ub1[16 * nt + 4 * g + r];
            cf[nt][r] = cvec[16 * nt + 4 * g + r];
            b2f[nt][r] = ub2[16 * nt + 4 * g + r];
            b1nf[nt][r] = b1n[16 * nt + 4 * g + r];
        }

    const int ntiles = NN / 16;
    for (int t = wid; t < ntiles; t += nw) {
        const int node = t * 16 + m16;
        bf16x8 hfr[2], sfr[2];
        hfr[0] = load_frag(h + node * 64 + 4 * g);
        hfr[1] = load_frag(h + node * 64 + 4 * g + 32);
        sfr[0] = load_frag(S + node * 64 + 4 * g);
        sfr[1] = load_frag(S + node * 64 + 4 * g + 32);
        float dv = (float)deg[node];

        f32x4 acc1[4];
        #pragma unroll
        for (int nt = 0; nt < 4; ++nt) acc1[nt] = (f32x4){0.f, 0.f, 0.f, 0.f};
        #pragma unroll
        for (int s = 0; s < 2; ++s)
            #pragma unroll
            for (int nt = 0; nt < 4; ++nt) {
                acc1[nt] = __builtin_amdgcn_mfma_f32_16x16x32_bf16(u1f[s][nt], hfr[s], acc1[nt], 0, 0, 0);
                acc1[nt] = __builtin_amdgcn_mfma_f32_16x16x32_bf16(w2f[s][nt], sfr[s], acc1[nt], 0, 0, 0);
            }

        bf16x8 hb[2];
        #pragma unroll
        for (int s = 0; s < 2; ++s) {
            bf16x8 f;
            #pragma unroll
            for (int half = 0; half < 2; ++half) {
                const int nt = 2 * s + half;
                #pragma unroll
                for (int r = 0; r < 4; ++r) {
                    float v = acc1[nt][r] + b1f[nt][r] + dv * cf[nt][r];
                    v = v > 0.f ? v : 0.f;
                    f[4 * half + r] = (bf16_t)v;
                }
            }
            hb[s] = f;
        }

        f32x4 acc2[4];
        #pragma unroll
        for (int nt = 0; nt < 4; ++nt) acc2[nt] = (f32x4){0.f, 0.f, 0.f, 0.f};
        #pragma unroll
        for (int s = 0; s < 2; ++s)
            #pragma unroll
            for (int nt = 0; nt < 4; ++nt)
                acc2[nt] = __builtin_amdgcn_mfma_f32_16x16x32_bf16(u2f[s][nt], hb[s], acc2[nt], 0, 0, 0);

        // h_new in B-fragment form (register renaming of acc2)
        bf16x8 hb2[2];
        #pragma unroll
        for (int s = 0; s < 2; ++s) {
            bf16x8 f;
            #pragma unroll
            for (int half = 0; half < 2; ++half) {
                const int nt = 2 * s + half;
                #pragma unroll
                for (int r = 0; r < 4; ++r) {
                    float v = acc2[nt][r] + b2f[nt][r];
                    f[4 * half + r] = (bf16_t)(v > 0.f ? v : 0.f);
                }
            }
            hb2[s] = f;
        }
        #pragma unroll
        for (int s = 0; s < 2; ++s) {
            bf16x4 lo, hi;
            #pragma unroll
            for (int j = 0; j < 4; ++j) { lo[j] = hb2[s][j]; hi[j] = hb2[s][4 + j]; }
            *(bf16x4*)(hn + node * 64 + 32 * s + 4 * g) = lo;
            *(bf16x4*)(hn + node * 64 + 32 * s + 16 + 4 * g) = hi;
        }

        // next-layer P/Q directly from hb2
        f32x4 accP[4], accQ[4];
        #pragma unroll
        for (int nt = 0; nt < 4; ++nt) {
            accP[nt] = (f32x4){0.f, 0.f, 0.f, 0.f};
            accQ[nt] = (f32x4){0.f, 0.f, 0.f, 0.f};
        }
        #pragma unroll
        for (int s = 0; s < 2; ++s)
            #pragma unroll
            for (int nt = 0; nt < 4; ++nt) {
                accP[nt] = __builtin_amdgcn_mfma_f32_16x16x32_bf16(wtop[s][nt], hb2[s], accP[nt], 0, 0, 0);
                accQ[nt] = __builtin_amdgcn_mfma_f32_16x16x32_bf16(wbot[s][nt], hb2[s], accQ[nt], 0, 0, 0);
            }
        #pragma unroll
        for (int nt = 0; nt < 4; ++nt) {
            bf16x4 vp, vq;
            #pragma unroll
            for (int r = 0; r < 4; ++r) {
                vp[r] = (bf16_t)accP[nt][r];
                vq[r] = (bf16_t)(accQ[nt][r] + b1nf[nt][r]);
            }
            *(bf16x4*)(P + node * 64 + 16 * nt + 4 * g) = vp;
            *(bf16x4*)(Q + node * 64 + 16 * nt + 4 * g) = vq;
        }
    }
}

// ---------------- plain update (last layer) ----------------
__global__ void k_upd(const bf16_t* __restrict__ h, const bf16_t* __restrict__ S,
                      const int* __restrict__ deg,
                      const bf16_t* __restrict__ u1t, const bf16_t* __restrict__ w2u,
                      const bf16_t* __restrict__ u2t,
                      const float* __restrict__ ub1, const float* __restrict__ cvec,
                      const float* __restrict__ ub2, bf16_t* __restrict__ hn) {
    const int lane = threadIdx.x & 63;
    const int g = lane >> 4;
    const int m16 = lane & 15;
    const int wid = (blockIdx.x * blockDim.x + threadIdx.x) >> 6;
    const int nw = (gridDim.x * blockDim.x) >> 6;

    bf16x8 u1f[2][4], w2f[2][4], u2f[2][4];
    #pragma unroll
    for (int s = 0; s < 2; ++s)
        #pragma unroll
        for (int nt = 0; nt < 4; ++nt) {
            u1f[s][nt] = load_frag(u1t + (16 * nt + m16) * 64 + 32 * s + 4 * g);
            w2f[s][nt] = load_frag(w2u + (16 * nt + m16) * 64 + 32 * s + 4 * g);
            u2f[s][nt] = load_frag(u2t + (16 * nt + m16) * 64 + 32 * s + 4 * g);
        }
    float b1f[4][4], cf[4][4], b2f[4][4];
    #pragma unroll
    for (int nt = 0; nt < 4; ++nt)
        #pragma unroll
        for (int r = 0; r < 4; ++r) {
            b1f[nt][r] = ub1[16 * nt + 4 * g + r];
            cf[nt][r] = cvec[16 * nt + 4 * g + r];
            b2f[nt][r] = ub2[16 * nt + 4 * g + r];
        }

    const int ntiles = NN / 16;
    for (int t = wid; t < ntiles; t += nw) {
        const int node = t * 16 + m16;
        bf16x8 hfr[2], sfr[2];
        hfr[0] = load_frag(h + node * 64 + 4 * g);
        hfr[1] = load_frag(h + node * 64 + 4 * g + 32);
        sfr[0] = load_frag(S + node * 64 + 4 * g);
        sfr[1] = load_frag(S + node * 64 + 4 * g + 32);
        float dv = (float)deg[node];

        f32x4 acc1[4];
        #pragma unroll
        for (int nt = 0; nt < 4; ++nt) acc1[nt] = (f32x4){0.f, 0.f, 0.f, 0.f};
        #pragma unroll
        for (int s = 0; s < 2; ++s)
            #pragma unroll
            for (int nt = 0; nt < 4; ++nt) {
                acc1[nt] = __builtin_amdgcn_mfma_f32_16x16x32_bf16(u1f[s][nt], hfr[s], acc1[nt], 0, 0, 0);
                acc1[nt] = __builtin_amdgcn_mfma_f32_16x16x32_bf16(w2f[s][nt], sfr[s], acc1[nt], 0, 0, 0);
            }

        bf16x8 hb[2];
        #pragma unroll
        for (int s = 0; s < 2; ++s) {
            bf16x8 f;
            #pragma unroll
            for (int half = 0; half < 2; ++half) {
                const int nt = 2 * s + half;
                #pragma unroll
                for (int r = 0; r < 4; ++r) {
                    float v = acc1[nt][r] + b1f[nt][r] + dv * cf[nt][r];
                    v = v > 0.f ? v : 0.f;
                    f[4 * half + r] = (bf16_t)v;
                }
            }
            hb[s] = f;
        }

        f32x4 acc2[4];
        #pragma unroll
        for (int nt = 0; nt < 4; ++nt) acc2[nt] = (f32x4){0.f, 0.f, 0.f, 0.f};
        #pragma unroll
        for (int s = 0; s < 2; ++s)
            #pragma unroll
            for (int nt = 0; nt < 4; ++nt)
                acc2[nt] = __builtin_amdgcn_mfma_f32_16x16x32_bf16(u2f[s][nt], hb[s], acc2[nt], 0, 0, 0);

        #pragma unroll
        for (int nt = 0; nt < 4; ++nt) {
            bf16x4 v4;
            #pragma unroll
            for (int r = 0; r < 4; ++r) {
                float v = acc2[nt][r] + b2f[nt][r];
                v4[r] = (bf16_t)(v > 0.f ? v : 0.f);
            }
            *(bf16x4*)(hn + node * 64 + 16 * nt + 4 * g) = v4;
        }
    }
}

// ---------------- output projection (MFMA, split hi/lo weights) ----------------
__global__ __launch_bounds__(256)
void k_outm(const bf16_t* __restrict__ whi_t, const bf16_t* __restrict__ wlo_t,
            const bf16_t* __restrict__ h, const float* __restrict__ b,
            float* __restrict__ out) {
    const int lane = threadIdx.x & 63;
    const int g = lane >> 4;
    const int m16 = lane & 15;
    const int wid = (blockIdx.x * blockDim.x + threadIdx.x) >> 6;
    const int nw = (gridDim.x * blockDim.x) >> 6;

    bf16x8 whi[2][8], wlo[2][8];
    #pragma unroll
    for (int s = 0; s < 2; ++s)
        #pragma unroll
        for (int nt = 0; nt < 8; ++nt) {
            whi[s][nt] = load_frag(whi_t + (16 * nt + m16) * 64 + 32 * s + 4 * g);
            wlo[s][nt] = load_frag(wlo_t + (16 * nt + m16) * 64 + 32 * s + 4 * g);
        }
    f32x4 bfv[8];
    #pragma unroll
    for (int nt = 0; nt < 8; ++nt)
        #pragma unroll
        for (int r = 0; r < 4; ++r) bfv[nt][r] = b[16 * nt + 4 * g + r];

    const int ntiles = NN / 16;
    for (int t = wid; t < ntiles; t += nw) {
        const int node = t * 16 + m16;
        bf16x8 hfr[2];
        hfr[0] = load_frag(h + node * 64 + 4 * g);
        hfr[1] = load_frag(h + node * 64 + 4 * g + 32);

        f32x4 acc[8];
        #pragma unroll
        for (int nt = 0; nt < 8; ++nt) acc[nt] = (f32x4){0.f, 0.f, 0.f, 0.f};
        #pragma unroll
        for (int s = 0; s < 2; ++s)
            #pragma unroll
            for (int nt = 0; nt < 8; ++nt) {
                acc[nt] = __builtin_amdgcn_mfma_f32_16x16x32_bf16(whi[s][nt], hfr[s], acc[nt], 0, 0, 0);
                acc[nt] = __builtin_amdgcn_mfma_f32_16x16x32_bf16(wlo[s][nt], hfr[s], acc[nt], 0, 0, 0);
            }
        #pragma unroll
        for (int nt = 0; nt < 8; ++nt)
            *(f32x4*)(out + node * 128 + 16 * nt + 4 * g) = acc[nt] + bfv[nt];
    }
}

extern "C" void kernel_launch(void* const* d_in, const int* in_sizes, int n_in,
                              void* d_out, int out_size, void* d_ws, size_t ws_size,
                              hipStream_t stream) {
    const float* x      = (const float*)d_in[0];
    const int*   ei     = (const int*)d_in[1];
    const float* in_w   = (const float*)d_in[2];
    const float* in_b   = (const float*)d_in[3];
    const float* msg_w1 = (const float*)d_in[4];
    const float* msg_b1 = (const float*)d_in[5];
    const float* msg_w2 = (const float*)d_in[6];
    const float* msg_b2 = (const float*)d_in[7];
    const float* upd_w1 = (const float*)d_in[8];
    const float* upd_b1 = (const float*)d_in[9];
    const float* upd_w2 = (const float*)d_in[10];
    const float* upd_b2 = (const float*)d_in[11];
    const float* out_w  = (const float*)d_in[12];
    const float* out_b  = (const float*)d_in[13];
    float* out = (float*)d_out;

    char* ws = (char*)d_ws;
    bf16_t* h_a    = (bf16_t*)(ws);
    bf16_t* h_b    = (bf16_t*)(ws + 6400000);
    bf16_t* P      = (bf16_t*)(ws + 12800000);
    bf16_t* Q      = (bf16_t*)(ws + 19200000);
    bf16_t* S      = (bf16_t*)(ws + 25600000);
    int*    ssrc   = (int*)   (ws + 32000000);
    int*    deg    = (int*)   (ws + 35200000);
    int*    offs   = (int*)   (ws + 35400000);
    int*    cursor = (int*)   (ws + 35600128);
    int*    tscan  = (int*)   (ws + 35800192);
    int*    part   = (int*)   (ws + 36000256);
    int*    pscan  = (int*)   (ws + 36001280);
    bf16_t* w1t    = (bf16_t*)(ws + 36002304);
    bf16_t* u1t    = (bf16_t*)(ws + 36051456);
    bf16_t* u2t    = (bf16_t*)(ws + 36076032);
    bf16_t* w2u    = (bf16_t*)(ws + 36100608);
    float*  cvec   = (float*) (ws + 36125184);
    bf16_t* whi    = (bf16_t*)(ws + 36126208);   // 16 KB
    bf16_t* wlo    = (bf16_t*)(ws + 36142592);   // 16 KB

    // weight prep
    k_prep<<<96, 256, 0, stream>>>(msg_w1, upd_w1, upd_w2, w1t, u1t, u2t);
    k_prep2<<<48, 256, 0, stream>>>(msg_w2, msg_b2, upd_w1, w2u, cvec);
    k_prep3<<<32, 256, 0, stream>>>(out_w, whi, wlo);

    // counting sort of edges by destination
    hipMemsetAsync(deg, 0, NN * sizeof(int), stream);
    k_hist<<<(NE + 255) / 256, 256, 0, stream>>>(ei, deg);
    k_scan1<<<SCAN_BLKS, 256, 0, stream>>>(deg, tscan, part);
    k_scan2<<<1, 256, 0, stream>>>(part, pscan);
    k_scan3<<<SCAN_BLKS, 256, 0, stream>>>(tscan, pscan, offs, cursor);
    k_scatter<<<(NE + 255) / 256, 256, 0, stream>>>(ei, cursor, ssrc);

    // fused input projection + layer-0 P/Q
    k_inputpq<<<512, 256, 0, stream>>>(x, in_w, in_b, w1t, msg_b1, h_a, P, Q);

    bf16_t* hc = h_a;
    bf16_t* hn = h_b;
    for (int l = 0; l < 3; ++l) {
        k_edge<<<(NN * 8 + 255) / 256, 256, 0, stream>>>(P, Q, ssrc, offs, S);
        if (l < 2) {
            k_updpq<<<512, 256, 0, stream>>>(hc, S, deg,
                u1t + l * 4096, w2u + l * 4096, u2t + l * 4096,
                upd_b1 + l * 64, cvec + l * 64, upd_b2 + l * 64,
                w1t + (l + 1) * 8192, msg_b1 + (l + 1) * 64,
                hn, P, Q);
        } else {
            k_upd<<<512, 256, 0, stream>>>(hc, S, deg,
                u1t + l * 4096, w2u + l * 4096, u2t + l * 4096,
                upd_b1 + l * 64, cvec + l * 64, upd_b2 + l * 64, hn);
        }
        bf16_t* tmp = hc; hc = hn; hn = tmp;
    }
    k_outm<<<640, 256, 0, stream>>>(whi, wlo, hc, out_b, out);
}

// Round 11
// 388.136 us; speedup vs baseline: 1.7568x; 1.0028x over previous
//
#include <hip/hip_runtime.h>
#include <hip/hip_bf16.h>

#define NN 50000
#define NE 800000

typedef __bf16 bf16_t;
typedef bf16_t bf16x4 __attribute__((ext_vector_type(4)));
typedef bf16_t bf16x8 __attribute__((ext_vector_type(8)));
typedef float f32x4 __attribute__((ext_vector_type(4)));

// 8-element MFMA A/B fragment: {p[0..3], p[16..19]} (two k-halves of 16x16x32).
__device__ __forceinline__ bf16x8 load_frag(const bf16_t* p) {
    bf16x4 lo = *(const bf16x4*)p;
    bf16x4 hi = *(const bf16x4*)(p + 16);
    bf16x8 f;
    f[0] = lo[0]; f[1] = lo[1]; f[2] = lo[2]; f[3] = lo[3];
    f[4] = hi[0]; f[5] = hi[1]; f[6] = hi[2]; f[7] = hi[3];
    return f;
}

// fragment = bf16(f32(a) + f32(b)) element-wise, for split-S reconstruction
__device__ __forceinline__ bf16x8 load_frag2(const bf16_t* p, const bf16_t* q) {
    bf16x8 a = load_frag(p);
    bf16x8 b = load_frag(q);
    bf16x8 f;
    #pragma unroll
    for (int j = 0; j < 8; ++j) f[j] = (bf16_t)((float)a[j] + (float)b[j]);
    return f;
}

// ---------------- fused weight prep (was k_prep + k_prep2 + k_prep3) ----------------
__global__ void k_prepall(const float* __restrict__ mw1, const float* __restrict__ uw1,
                          const float* __restrict__ uw2,
                          const float* __restrict__ mw2, const float* __restrict__ mb2,
                          const float* __restrict__ ow,
                          bf16_t* __restrict__ w1t, bf16_t* __restrict__ u1t,
                          bf16_t* __restrict__ u2t,
                          bf16_t* __restrict__ w2u, float* __restrict__ cvec,
                          bf16_t* __restrict__ whi, bf16_t* __restrict__ wlo) {
    int gid = blockIdx.x * blockDim.x + threadIdx.x;
    if (gid < 3 * 64 * 128) {
        int l = gid / 8192, r = gid % 8192, hid = r >> 7, k = r & 127;
        w1t[gid] = (bf16_t)mw1[l * 8192 + k * 64 + hid];
    }
    if (gid < 3 * 64 * 64) {
        int l = gid / 4096, r = gid % 4096, hid = r >> 6, k = r & 63;
        u1t[gid] = (bf16_t)uw1[l * 8192 + k * 64 + hid];
        u2t[gid] = (bf16_t)uw2[l * 4096 + k * 64 + hid];
        float s = 0.f;
        for (int j = 0; j < 64; ++j)
            s += mw2[l * 4096 + k * 64 + j] * uw1[l * 8192 + (64 + j) * 64 + hid];
        w2u[l * 4096 + hid * 64 + k] = (bf16_t)s;
    }
    if (gid < 3 * 64) {
        int l = gid / 64, hid = gid % 64;
        float s = 0.f;
        for (int j = 0; j < 64; ++j)
            s += mb2[l * 64 + j] * uw1[l * 8192 + (64 + j) * 64 + hid];
        cvec[gid] = s;
    }
    if (gid < 128 * 64) {
        int j = gid >> 6, k = gid & 63;
        float w = ow[k * 128 + j];
        bf16_t hi = (bf16_t)w;
        whi[gid] = hi;
        wlo[gid] = (bf16_t)(w - (float)hi);
    }
}

// ---------------- counting sort of edges by destination ----------------
__global__ void k_hist(const int* __restrict__ ei, int* __restrict__ deg) {
    int gid = blockIdx.x * blockDim.x + threadIdx.x;
    if (gid < NE) atomicAdd(&deg[ei[NE + gid]], 1);
}

#define SCAN_BLKS 196
__global__ void k_scan1(const int* __restrict__ deg, int* __restrict__ tscan,
                        int* __restrict__ part) {
    __shared__ int lds[256];
    int tid = threadIdx.x;
    int gid = blockIdx.x * 256 + tid;
    int v = (gid < NN) ? deg[gid] : 0;
    lds[tid] = v;
    __syncthreads();
    for (int off = 1; off < 256; off <<= 1) {
        int t = (tid >= off) ? lds[tid - off] : 0;
        __syncthreads();
        lds[tid] += t;
        __syncthreads();
    }
    if (gid < NN) tscan[gid] = lds[tid] - v;
    if (tid == 255) part[blockIdx.x] = lds[255];
}

__global__ void k_scan2(const int* __restrict__ part, int* __restrict__ pscan) {
    __shared__ int lds[256];
    int tid = threadIdx.x;
    int v = (tid < SCAN_BLKS) ? part[tid] : 0;
    lds[tid] = v;
    __syncthreads();
    for (int off = 1; off < 256; off <<= 1) {
        int t = (tid >= off) ? lds[tid - off] : 0;
        __syncthreads();
        lds[tid] += t;
        __syncthreads();
    }
    pscan[tid] = lds[tid] - v;
}

__global__ void k_scan3(const int* __restrict__ tscan, const int* __restrict__ pscan,
                        int* __restrict__ offs, int* __restrict__ cursor) {
    int gid = blockIdx.x * blockDim.x + threadIdx.x;
    if (gid < NN) {
        int o = tscan[gid] + pscan[gid >> 8];
        offs[gid] = o;
        cursor[gid] = o;
    }
    if (gid == 0) offs[NN] = NE;
}

__global__ void k_scatter(const int* __restrict__ ei, int* __restrict__ cursor,
                          int* __restrict__ ssrc) {
    int gid = blockIdx.x * blockDim.x + threadIdx.x;
    if (gid < NE) {
        int c = ei[NE + gid];
        int pos = atomicAdd(&cursor[c], 1);
        ssrc[pos] = ei[gid];
    }
}

// ---------------- fused input projection + layer-0 P/Q ----------------
__global__ __launch_bounds__(256)
void k_inputpq(const float* __restrict__ x, const float* __restrict__ iw,
               const float* __restrict__ ib,
               const bf16_t* __restrict__ w1t, const float* __restrict__ b1,
               bf16_t* __restrict__ h, bf16_t* __restrict__ P, bf16_t* __restrict__ Q) {
    const int lane = threadIdx.x & 63;
    const int g = lane >> 4;
    const int m16 = lane & 15;
    const int wid = (blockIdx.x * blockDim.x + threadIdx.x) >> 6;
    const int nw = (gridDim.x * blockDim.x) >> 6;

    bf16x8 wtop[2][4], wbot[2][4];
    #pragma unroll
    for (int s = 0; s < 2; ++s)
        #pragma unroll
        for (int nt = 0; nt < 4; ++nt) {
            wtop[s][nt] = load_frag(w1t + (16 * nt + m16) * 128 + 32 * s + 4 * g);
            wbot[s][nt] = load_frag(w1t + (16 * nt + m16) * 128 + 64 + 32 * s + 4 * g);
        }
    float b1f[4][4];
    #pragma unroll
    for (int nt = 0; nt < 4; ++nt)
        #pragma unroll
        for (int r = 0; r < 4; ++r) b1f[nt][r] = b1[16 * nt + 4 * g + r];

    float wcol[3][2][8], bcol[2][8];
    #pragma unroll
    for (int s = 0; s < 2; ++s)
        #pragma unroll
        for (int j = 0; j < 8; ++j) {
            int f = 32 * s + 4 * g + (j < 4 ? j : 16 + j - 4);
            bcol[s][j] = ib[f];
            #pragma unroll
            for (int i = 0; i < 3; ++i) wcol[i][s][j] = iw[i * 64 + f];
        }

    const int ntiles = NN / 16;
    for (int t = wid; t < ntiles; t += nw) {
        const int node = t * 16 + m16;
        float x0 = x[node * 3 + 0], x1 = x[node * 3 + 1], x2 = x[node * 3 + 2];
        bf16x8 hb[2];
        #pragma unroll
        for (int s = 0; s < 2; ++s)
            #pragma unroll
            for (int j = 0; j < 8; ++j) {
                float hf = bcol[s][j] + x0 * wcol[0][s][j] + x1 * wcol[1][s][j]
                         + x2 * wcol[2][s][j];
                hb[s][j] = (bf16_t)hf;
            }
        #pragma unroll
        for (int s = 0; s < 2; ++s) {
            bf16x4 lo, hi;
            #pragma unroll
            for (int j = 0; j < 4; ++j) { lo[j] = hb[s][j]; hi[j] = hb[s][4 + j]; }
            *(bf16x4*)(h + node * 64 + 32 * s + 4 * g) = lo;
            *(bf16x4*)(h + node * 64 + 32 * s + 16 + 4 * g) = hi;
        }

        f32x4 accP[4], accQ[4];
        #pragma unroll
        for (int nt = 0; nt < 4; ++nt) {
            accP[nt] = (f32x4){0.f, 0.f, 0.f, 0.f};
            accQ[nt] = (f32x4){0.f, 0.f, 0.f, 0.f};
        }
        #pragma unroll
        for (int s = 0; s < 2; ++s)
            #pragma unroll
            for (int nt = 0; nt < 4; ++nt) {
                accP[nt] = __builtin_amdgcn_mfma_f32_16x16x32_bf16(wtop[s][nt], hb[s], accP[nt], 0, 0, 0);
                accQ[nt] = __builtin_amdgcn_mfma_f32_16x16x32_bf16(wbot[s][nt], hb[s], accQ[nt], 0, 0, 0);
            }
        #pragma unroll
        for (int nt = 0; nt < 4; ++nt) {
            bf16x4 vp, vq;
            #pragma unroll
            for (int r = 0; r < 4; ++r) {
                vp[r] = (bf16_t)accP[nt][r];
                vq[r] = (bf16_t)(accQ[nt][r] + b1f[nt][r]);
            }
            *(bf16x4*)(P + node * 64 + 16 * nt + 4 * g) = vp;
            *(bf16x4*)(Q + node * 64 + 16 * nt + 4 * g) = vq;
        }
    }
}

// ---------------- per-layer edge phase, split-2 ----------------
// thread = (node, half, feature-octet): each node's edge list is split across
// TWO octet groups writing partial sums to S (half 0) / S2 (half 1) — no
// atomics, no combine kernel (k_upd adds the halves at fragment build).
// 2x threads (~8 waves/SIMD), half the serial chain, imbalance 1.7x -> 1.5x.
__global__ void k_edge(const bf16_t* __restrict__ P, const bf16_t* __restrict__ Q,
                       const int* __restrict__ ssrc, const int* __restrict__ offs,
                       bf16_t* __restrict__ S, bf16_t* __restrict__ S2) {
    int gid = blockIdx.x * blockDim.x + threadIdx.x;
    int oct = gid >> 3, f8 = gid & 7;
    int node = oct >> 1, half = oct & 1;
    if (node >= NN) return;
    bf16x8 qv = *(const bf16x8*)(Q + node * 64 + f8 * 8);
    float qf[8], a[8];
    #pragma unroll
    for (int r = 0; r < 8; ++r) { qf[r] = (float)qv[r]; a[r] = 0.f; }
    const int b0 = offs[node], e0 = offs[node + 1];
    const int mid = b0 + ((e0 - b0 + 1) >> 1);
    const int beg = half ? mid : b0;
    const int end = half ? e0 : mid;
    int p = beg;
    const int n4 = beg + ((end - beg) & ~3);
    for (; p < n4; p += 4) {
        int s0 = ssrc[p], s1 = ssrc[p + 1], s2 = ssrc[p + 2], s3 = ssrc[p + 3];
        bf16x8 v0 = *(const bf16x8*)(P + s0 * 64 + f8 * 8);
        bf16x8 v1 = *(const bf16x8*)(P + s1 * 64 + f8 * 8);
        bf16x8 v2 = *(const bf16x8*)(P + s2 * 64 + f8 * 8);
        bf16x8 v3 = *(const bf16x8*)(P + s3 * 64 + f8 * 8);
        #pragma unroll
        for (int r = 0; r < 8; ++r) {
            float x0 = (float)v0[r] + qf[r];
            float x1 = (float)v1[r] + qf[r];
            float x2 = (float)v2[r] + qf[r];
            float x3 = (float)v3[r] + qf[r];
            a[r] += (x0 > 0.f ? x0 : 0.f) + (x1 > 0.f ? x1 : 0.f)
                  + (x2 > 0.f ? x2 : 0.f) + (x3 > 0.f ? x3 : 0.f);
        }
    }
    for (; p < end; ++p) {
        int s = ssrc[p];
        bf16x8 v = *(const bf16x8*)(P + s * 64 + f8 * 8);
        #pragma unroll
        for (int r = 0; r < 8; ++r) {
            float x = (float)v[r] + qf[r];
            a[r] += x > 0.f ? x : 0.f;
        }
    }
    bf16x8 sv;
    #pragma unroll
    for (int r = 0; r < 8; ++r) sv[r] = (bf16_t)a[r];
    bf16_t* dst = half ? S2 : S;
    *(bf16x8*)(dst + node * 64 + f8 * 8) = sv;
}

// ---------------- fused update + next-layer P/Q ----------------
__global__ __launch_bounds__(256)
void k_updpq(const bf16_t* __restrict__ h, const bf16_t* __restrict__ S,
             const bf16_t* __restrict__ S2, const int* __restrict__ deg,
             const bf16_t* __restrict__ u1t, const bf16_t* __restrict__ w2u,
             const bf16_t* __restrict__ u2t,
             const float* __restrict__ ub1, const float* __restrict__ cvec,
             const float* __restrict__ ub2,
             const bf16_t* __restrict__ w1tn, const float* __restrict__ b1n,
             bf16_t* __restrict__ hn, bf16_t* __restrict__ P, bf16_t* __restrict__ Q) {
    const int lane = threadIdx.x & 63;
    const int g = lane >> 4;
    const int m16 = lane & 15;
    const int wid = (blockIdx.x * blockDim.x + threadIdx.x) >> 6;
    const int nw = (gridDim.x * blockDim.x) >> 6;

    bf16x8 u1f[2][4], w2f[2][4], u2f[2][4], wtop[2][4], wbot[2][4];
    #pragma unroll
    for (int s = 0; s < 2; ++s)
        #pragma unroll
        for (int nt = 0; nt < 4; ++nt) {
            u1f[s][nt] = load_frag(u1t + (16 * nt + m16) * 64 + 32 * s + 4 * g);
            w2f[s][nt] = load_frag(w2u + (16 * nt + m16) * 64 + 32 * s + 4 * g);
            u2f[s][nt] = load_frag(u2t + (16 * nt + m16) * 64 + 32 * s + 4 * g);
            wtop[s][nt] = load_frag(w1tn + (16 * nt + m16) * 128 + 32 * s + 4 * g);
            wbot[s][nt] = load_frag(w1tn + (16 * nt + m16) * 128 + 64 + 32 * s + 4 * g);
        }
    float b1f[4][4], cf[4][4], b2f[4][4], b1nf[4][4];
    #pragma unroll
    for (int nt = 0; nt < 4; ++nt)
        #pragma unroll
        for (int r = 0; r < 4; ++r) {
            b1f[nt][r] = ub1[16 * nt + 4 * g + r];
            cf[nt][r] = cvec[16 * nt + 4 * g + r];
            b2f[nt][r] = ub2[16 * nt + 4 * g + r];
            b1nf[nt][r] = b1n[16 * nt + 4 * g + r];
        }

    const int ntiles = NN / 16;
    for (int t = wid; t < ntiles; t += nw) {
        const int node = t * 16 + m16;
        bf16x8 hfr[2], sfr[2];
        hfr[0] = load_frag(h + node * 64 + 4 * g);
        hfr[1] = load_frag(h + node * 64 + 4 * g + 32);
        sfr[0] = load_frag2(S + node * 64 + 4 * g, S2 + node * 64 + 4 * g);
        sfr[1] = load_frag2(S + node * 64 + 4 * g + 32, S2 + node * 64 + 4 * g + 32);
        float dv = (float)deg[node];

        f32x4 acc1[4];
        #pragma unroll
        for (int nt = 0; nt < 4; ++nt) acc1[nt] = (f32x4){0.f, 0.f, 0.f, 0.f};
        #pragma unroll
        for (int s = 0; s < 2; ++s)
            #pragma unroll
            for (int nt = 0; nt < 4; ++nt) {
                acc1[nt] = __builtin_amdgcn_mfma_f32_16x16x32_bf16(u1f[s][nt], hfr[s], acc1[nt], 0, 0, 0);
                acc1[nt] = __builtin_amdgcn_mfma_f32_16x16x32_bf16(w2f[s][nt], sfr[s], acc1[nt], 0, 0, 0);
            }

        bf16x8 hb[2];
        #pragma unroll
        for (int s = 0; s < 2; ++s) {
            bf16x8 f;
            #pragma unroll
            for (int half = 0; half < 2; ++half) {
                const int nt = 2 * s + half;
                #pragma unroll
                for (int r = 0; r < 4; ++r) {
                    float v = acc1[nt][r] + b1f[nt][r] + dv * cf[nt][r];
                    v = v > 0.f ? v : 0.f;
                    f[4 * half + r] = (bf16_t)v;
                }
            }
            hb[s] = f;
        }

        f32x4 acc2[4];
        #pragma unroll
        for (int nt = 0; nt < 4; ++nt) acc2[nt] = (f32x4){0.f, 0.f, 0.f, 0.f};
        #pragma unroll
        for (int s = 0; s < 2; ++s)
            #pragma unroll
            for (int nt = 0; nt < 4; ++nt)
                acc2[nt] = __builtin_amdgcn_mfma_f32_16x16x32_bf16(u2f[s][nt], hb[s], acc2[nt], 0, 0, 0);

        bf16x8 hb2[2];
        #pragma unroll
        for (int s = 0; s < 2; ++s) {
            bf16x8 f;
            #pragma unroll
            for (int half = 0; half < 2; ++half) {
                const int nt = 2 * s + half;
                #pragma unroll
                for (int r = 0; r < 4; ++r) {
                    float v = acc2[nt][r] + b2f[nt][r];
                    f[4 * half + r] = (bf16_t)(v > 0.f ? v : 0.f);
                }
            }
            hb2[s] = f;
        }
        #pragma unroll
        for (int s = 0; s < 2; ++s) {
            bf16x4 lo, hi;
            #pragma unroll
            for (int j = 0; j < 4; ++j) { lo[j] = hb2[s][j]; hi[j] = hb2[s][4 + j]; }
            *(bf16x4*)(hn + node * 64 + 32 * s + 4 * g) = lo;
            *(bf16x4*)(hn + node * 64 + 32 * s + 16 + 4 * g) = hi;
        }

        f32x4 accP[4], accQ[4];
        #pragma unroll
        for (int nt = 0; nt < 4; ++nt) {
            accP[nt] = (f32x4){0.f, 0.f, 0.f, 0.f};
            accQ[nt] = (f32x4){0.f, 0.f, 0.f, 0.f};
        }
        #pragma unroll
        for (int s = 0; s < 2; ++s)
            #pragma unroll
            for (int nt = 0; nt < 4; ++nt) {
                accP[nt] = __builtin_amdgcn_mfma_f32_16x16x32_bf16(wtop[s][nt], hb2[s], accP[nt], 0, 0, 0);
                accQ[nt] = __builtin_amdgcn_mfma_f32_16x16x32_bf16(wbot[s][nt], hb2[s], accQ[nt], 0, 0, 0);
            }
        #pragma unroll
        for (int nt = 0; nt < 4; ++nt) {
            bf16x4 vp, vq;
            #pragma unroll
            for (int r = 0; r < 4; ++r) {
                vp[r] = (bf16_t)accP[nt][r];
                vq[r] = (bf16_t)(accQ[nt][r] + b1nf[nt][r]);
            }
            *(bf16x4*)(P + node * 64 + 16 * nt + 4 * g) = vp;
            *(bf16x4*)(Q + node * 64 + 16 * nt + 4 * g) = vq;
        }
    }
}

// ---------------- plain update (last layer) ----------------
__global__ void k_upd(const bf16_t* __restrict__ h, const bf16_t* __restrict__ S,
                      const bf16_t* __restrict__ S2, const int* __restrict__ deg,
                      const bf16_t* __restrict__ u1t, const bf16_t* __restrict__ w2u,
                      const bf16_t* __restrict__ u2t,
                      const float* __restrict__ ub1, const float* __restrict__ cvec,
                      const float* __restrict__ ub2, bf16_t* __restrict__ hn) {
    const int lane = threadIdx.x & 63;
    const int g = lane >> 4;
    const int m16 = lane & 15;
    const int wid = (blockIdx.x * blockDim.x + threadIdx.x) >> 6;
    const int nw = (gridDim.x * blockDim.x) >> 6;

    bf16x8 u1f[2][4], w2f[2][4], u2f[2][4];
    #pragma unroll
    for (int s = 0; s < 2; ++s)
        #pragma unroll
        for (int nt = 0; nt < 4; ++nt) {
            u1f[s][nt] = load_frag(u1t + (16 * nt + m16) * 64 + 32 * s + 4 * g);
            w2f[s][nt] = load_frag(w2u + (16 * nt + m16) * 64 + 32 * s + 4 * g);
            u2f[s][nt] = load_frag(u2t + (16 * nt + m16) * 64 + 32 * s + 4 * g);
        }
    float b1f[4][4], cf[4][4], b2f[4][4];
    #pragma unroll
    for (int nt = 0; nt < 4; ++nt)
        #pragma unroll
        for (int r = 0; r < 4; ++r) {
            b1f[nt][r] = ub1[16 * nt + 4 * g + r];
            cf[nt][r] = cvec[16 * nt + 4 * g + r];
            b2f[nt][r] = ub2[16 * nt + 4 * g + r];
        }

    const int ntiles = NN / 16;
    for (int t = wid; t < ntiles; t += nw) {
        const int node = t * 16 + m16;
        bf16x8 hfr[2], sfr[2];
        hfr[0] = load_frag(h + node * 64 + 4 * g);
        hfr[1] = load_frag(h + node * 64 + 4 * g + 32);
        sfr[0] = load_frag2(S + node * 64 + 4 * g, S2 + node * 64 + 4 * g);
        sfr[1] = load_frag2(S + node * 64 + 4 * g + 32, S2 + node * 64 + 4 * g + 32);
        float dv = (float)deg[node];

        f32x4 acc1[4];
        #pragma unroll
        for (int nt = 0; nt < 4; ++nt) acc1[nt] = (f32x4){0.f, 0.f, 0.f, 0.f};
        #pragma unroll
        for (int s = 0; s < 2; ++s)
            #pragma unroll
            for (int nt = 0; nt < 4; ++nt) {
                acc1[nt] = __builtin_amdgcn_mfma_f32_16x16x32_bf16(u1f[s][nt], hfr[s], acc1[nt], 0, 0, 0);
                acc1[nt] = __builtin_amdgcn_mfma_f32_16x16x32_bf16(w2f[s][nt], sfr[s], acc1[nt], 0, 0, 0);
            }

        bf16x8 hb[2];
        #pragma unroll
        for (int s = 0; s < 2; ++s) {
            bf16x8 f;
            #pragma unroll
            for (int half = 0; half < 2; ++half) {
                const int nt = 2 * s + half;
                #pragma unroll
                for (int r = 0; r < 4; ++r) {
                    float v = acc1[nt][r] + b1f[nt][r] + dv * cf[nt][r];
                    v = v > 0.f ? v : 0.f;
                    f[4 * half + r] = (bf16_t)v;
                }
            }
            hb[s] = f;
        }

        f32x4 acc2[4];
        #pragma unroll
        for (int nt = 0; nt < 4; ++nt) acc2[nt] = (f32x4){0.f, 0.f, 0.f, 0.f};
        #pragma unroll
        for (int s = 0; s < 2; ++s)
            #pragma unroll
            for (int nt = 0; nt < 4; ++nt)
                acc2[nt] = __builtin_amdgcn_mfma_f32_16x16x32_bf16(u2f[s][nt], hb[s], acc2[nt], 0, 0, 0);

        #pragma unroll
        for (int nt = 0; nt < 4; ++nt) {
            bf16x4 v4;
            #pragma unroll
            for (int r = 0; r < 4; ++r) {
                float v = acc2[nt][r] + b2f[nt][r];
                v4[r] = (bf16_t)(v > 0.f ? v : 0.f);
            }
            *(bf16x4*)(hn + node * 64 + 16 * nt + 4 * g) = v4;
        }
    }
}

// ---------------- output projection (MFMA, split hi/lo weights) ----------------
__global__ __launch_bounds__(256)
void k_outm(const bf16_t* __restrict__ whi_t, const bf16_t* __restrict__ wlo_t,
            const bf16_t* __restrict__ h, const float* __restrict__ b,
            float* __restrict__ out) {
    const int lane = threadIdx.x & 63;
    const int g = lane >> 4;
    const int m16 = lane & 15;
    const int wid = (blockIdx.x * blockDim.x + threadIdx.x) >> 6;
    const int nw = (gridDim.x * blockDim.x) >> 6;

    bf16x8 whi[2][8], wlo[2][8];
    #pragma unroll
    for (int s = 0; s < 2; ++s)
        #pragma unroll
        for (int nt = 0; nt < 8; ++nt) {
            whi[s][nt] = load_frag(whi_t + (16 * nt + m16) * 64 + 32 * s + 4 * g);
            wlo[s][nt] = load_frag(wlo_t + (16 * nt + m16) * 64 + 32 * s + 4 * g);
        }
    f32x4 bfv[8];
    #pragma unroll
    for (int nt = 0; nt < 8; ++nt)
        #pragma unroll
        for (int r = 0; r < 4; ++r) bfv[nt][r] = b[16 * nt + 4 * g + r];

    const int ntiles = NN / 16;
    for (int t = wid; t < ntiles; t += nw) {
        const int node = t * 16 + m16;
        bf16x8 hfr[2];
        hfr[0] = load_frag(h + node * 64 + 4 * g);
        hfr[1] = load_frag(h + node * 64 + 4 * g + 32);

        f32x4 acc[8];
        #pragma unroll
        for (int nt = 0; nt < 8; ++nt) acc[nt] = (f32x4){0.f, 0.f, 0.f, 0.f};
        #pragma unroll
        for (int s = 0; s < 2; ++s)
            #pragma unroll
            for (int nt = 0; nt < 8; ++nt) {
                acc[nt] = __builtin_amdgcn_mfma_f32_16x16x32_bf16(whi[s][nt], hfr[s], acc[nt], 0, 0, 0);
                acc[nt] = __builtin_amdgcn_mfma_f32_16x16x32_bf16(wlo[s][nt], hfr[s], acc[nt], 0, 0, 0);
            }
        #pragma unroll
        for (int nt = 0; nt < 8; ++nt)
            *(f32x4*)(out + node * 128 + 16 * nt + 4 * g) = acc[nt] + bfv[nt];
    }
}

extern "C" void kernel_launch(void* const* d_in, const int* in_sizes, int n_in,
                              void* d_out, int out_size, void* d_ws, size_t ws_size,
                              hipStream_t stream) {
    const float* x      = (const float*)d_in[0];
    const int*   ei     = (const int*)d_in[1];
    const float* in_w   = (const float*)d_in[2];
    const float* in_b   = (const float*)d_in[3];
    const float* msg_w1 = (const float*)d_in[4];
    const float* msg_b1 = (const float*)d_in[5];
    const float* msg_w2 = (const float*)d_in[6];
    const float* msg_b2 = (const float*)d_in[7];
    const float* upd_w1 = (const float*)d_in[8];
    const float* upd_b1 = (const float*)d_in[9];
    const float* upd_w2 = (const float*)d_in[10];
    const float* upd_b2 = (const float*)d_in[11];
    const float* out_w  = (const float*)d_in[12];
    const float* out_b  = (const float*)d_in[13];
    float* out = (float*)d_out;

    char* ws = (char*)d_ws;
    bf16_t* h_a    = (bf16_t*)(ws);
    bf16_t* h_b    = (bf16_t*)(ws + 6400000);
    bf16_t* P      = (bf16_t*)(ws + 12800000);
    bf16_t* Q      = (bf16_t*)(ws + 19200000);
    bf16_t* S      = (bf16_t*)(ws + 25600000);
    int*    ssrc   = (int*)   (ws + 32000000);
    int*    deg    = (int*)   (ws + 35200000);
    int*    offs   = (int*)   (ws + 35400000);
    int*    cursor = (int*)   (ws + 35600128);
    int*    tscan  = (int*)   (ws + 35800192);
    int*    part   = (int*)   (ws + 36000256);
    int*    pscan  = (int*)   (ws + 36001280);
    bf16_t* w1t    = (bf16_t*)(ws + 36002304);
    bf16_t* u1t    = (bf16_t*)(ws + 36051456);
    bf16_t* u2t    = (bf16_t*)(ws + 36076032);
    bf16_t* w2u    = (bf16_t*)(ws + 36100608);
    float*  cvec   = (float*) (ws + 36125184);
    bf16_t* whi    = (bf16_t*)(ws + 36126208);   // 16 KB
    bf16_t* wlo    = (bf16_t*)(ws + 36142592);   // 16 KB
    bf16_t* S2     = (bf16_t*)(ws + 36160000);   // 6.4 MB

    // fused weight prep
    k_prepall<<<96, 256, 0, stream>>>(msg_w1, upd_w1, upd_w2, msg_w2, msg_b2, out_w,
                                      w1t, u1t, u2t, w2u, cvec, whi, wlo);

    // counting sort of edges by destination
    hipMemsetAsync(deg, 0, NN * sizeof(int), stream);
    k_hist<<<(NE + 255) / 256, 256, 0, stream>>>(ei, deg);
    k_scan1<<<SCAN_BLKS, 256, 0, stream>>>(deg, tscan, part);
    k_scan2<<<1, 256, 0, stream>>>(part, pscan);
    k_scan3<<<SCAN_BLKS, 256, 0, stream>>>(tscan, pscan, offs, cursor);
    k_scatter<<<(NE + 255) / 256, 256, 0, stream>>>(ei, cursor, ssrc);

    // fused input projection + layer-0 P/Q
    k_inputpq<<<512, 256, 0, stream>>>(x, in_w, in_b, w1t, msg_b1, h_a, P, Q);

    bf16_t* hc = h_a;
    bf16_t* hn = h_b;
    for (int l = 0; l < 3; ++l) {
        k_edge<<<(NN * 16 + 255) / 256, 256, 0, stream>>>(P, Q, ssrc, offs, S, S2);
        if (l < 2) {
            k_updpq<<<512, 256, 0, stream>>>(hc, S, S2, deg,
                u1t + l * 4096, w2u + l * 4096, u2t + l * 4096,
                upd_b1 + l * 64, cvec + l * 64, upd_b2 + l * 64,
                w1t + (l + 1) * 8192, msg_b1 + (l + 1) * 64,
                hn, P, Q);
        } else {
            k_upd<<<512, 256, 0, stream>>>(hc, S, S2, deg,
                u1t + l * 4096, w2u + l * 4096, u2t + l * 4096,
                upd_b1 + l * 64, cvec + l * 64, upd_b2 + l * 64, hn);
        }
        bf16_t* tmp = hc; hc = hn; hn = tmp;
    }
    k_outm<<<640, 256, 0, stream>>>(whi, wlo, hc, out_b, out);
}

// Round 13
// 373.811 us; speedup vs baseline: 1.8242x; 1.0383x over previous
//
#include <hip/hip_runtime.h>
#include <hip/hip_bf16.h>

#define NN 50000
#define NE 800000

typedef __bf16 bf16_t;
typedef unsigned short u16;
typedef bf16_t bf16x4 __attribute__((ext_vector_type(4)));
typedef bf16_t bf16x8 __attribute__((ext_vector_type(8)));
typedef float f32x4 __attribute__((ext_vector_type(4)));

// 8-element MFMA A/B fragment: {p[0..3], p[16..19]} (two k-halves of 16x16x32).
__device__ __forceinline__ bf16x8 load_frag(const bf16_t* p) {
    bf16x4 lo = *(const bf16x4*)p;
    bf16x4 hi = *(const bf16x4*)(p + 16);
    bf16x8 f;
    f[0] = lo[0]; f[1] = lo[1]; f[2] = lo[2]; f[3] = lo[3];
    f[4] = hi[0]; f[5] = hi[1]; f[6] = hi[2]; f[7] = hi[3];
    return f;
}

// fragment = bf16(f32(a) + f32(b)) element-wise, for split-S reconstruction
__device__ __forceinline__ bf16x8 load_frag2(const bf16_t* p, const bf16_t* q) {
    bf16x8 a = load_frag(p);
    bf16x8 b = load_frag(q);
    bf16x8 f;
    #pragma unroll
    for (int j = 0; j < 8; ++j) f[j] = (bf16_t)((float)a[j] + (float)b[j]);
    return f;
}

// ---------------- fused weight prep (+ deg zeroing, replacing memset) ----------------
__global__ void k_prepall(const float* __restrict__ mw1, const float* __restrict__ uw1,
                          const float* __restrict__ uw2,
                          const float* __restrict__ mw2, const float* __restrict__ mb2,
                          const float* __restrict__ ow,
                          bf16_t* __restrict__ w1t, bf16_t* __restrict__ u1t,
                          bf16_t* __restrict__ u2t,
                          bf16_t* __restrict__ w2u, float* __restrict__ cvec,
                          bf16_t* __restrict__ whi, bf16_t* __restrict__ wlo,
                          int* __restrict__ deg) {
    int gid = blockIdx.x * blockDim.x + threadIdx.x;
    int nthr = gridDim.x * blockDim.x;
    for (int i = gid; i < NN; i += nthr) deg[i] = 0;
    if (gid < 3 * 64 * 128) {
        int l = gid / 8192, r = gid % 8192, hid = r >> 7, k = r & 127;
        w1t[gid] = (bf16_t)mw1[l * 8192 + k * 64 + hid];
    }
    if (gid < 3 * 64 * 64) {
        int l = gid / 4096, r = gid % 4096, hid = r >> 6, k = r & 63;
        u1t[gid] = (bf16_t)uw1[l * 8192 + k * 64 + hid];
        u2t[gid] = (bf16_t)uw2[l * 4096 + k * 64 + hid];
        float s = 0.f;
        for (int j = 0; j < 64; ++j)
            s += mw2[l * 4096 + k * 64 + j] * uw1[l * 8192 + (64 + j) * 64 + hid];
        w2u[l * 4096 + hid * 64 + k] = (bf16_t)s;
    }
    if (gid < 3 * 64) {
        int l = gid / 64, hid = gid % 64;
        float s = 0.f;
        for (int j = 0; j < 64; ++j)
            s += mb2[l * 64 + j] * uw1[l * 8192 + (64 + j) * 64 + hid];
        cvec[gid] = s;
    }
    if (gid < 128 * 64) {
        int j = gid >> 6, k = gid & 63;
        float w = ow[k * 128 + j];
        bf16_t hi = (bf16_t)w;
        whi[gid] = hi;
        wlo[gid] = (bf16_t)(w - (float)hi);
    }
}

// ---------------- counting sort of edges by destination ----------------
__global__ void k_hist(const int* __restrict__ ei, int* __restrict__ deg) {
    int gid = blockIdx.x * blockDim.x + threadIdx.x;
    if (gid < NE) atomicAdd(&deg[ei[NE + gid]], 1);
}

#define SCAN_BLKS 196
__global__ void k_scan1(const int* __restrict__ deg, int* __restrict__ tscan,
                        int* __restrict__ part) {
    __shared__ int lds[256];
    int tid = threadIdx.x;
    int gid = blockIdx.x * 256 + tid;
    int v = (gid < NN) ? deg[gid] : 0;
    lds[tid] = v;
    __syncthreads();
    for (int off = 1; off < 256; off <<= 1) {
        int t = (tid >= off) ? lds[tid - off] : 0;
        __syncthreads();
        lds[tid] += t;
        __syncthreads();
    }
    if (gid < NN) tscan[gid] = lds[tid] - v;
    if (tid == 255) part[blockIdx.x] = lds[255];
}

// fused scan2+scan3: every block redundantly scans the 196 partials in LDS,
// picks its own exclusive prefix, then finalizes offs/cursor for its chunk.
__global__ void k_scan23(const int* __restrict__ tscan, const int* __restrict__ part,
                         int* __restrict__ offs, int* __restrict__ cursor) {
    __shared__ int lds[256];
    int tid = threadIdx.x;
    int v = (tid < SCAN_BLKS) ? part[tid] : 0;
    lds[tid] = v;
    __syncthreads();
    for (int off = 1; off < 256; off <<= 1) {
        int t = (tid >= off) ? lds[tid - off] : 0;
        __syncthreads();
        lds[tid] += t;
        __syncthreads();
    }
    // exclusive prefix for this block
    __shared__ int base;
    if (tid == 0) base = (blockIdx.x > 0) ? lds[blockIdx.x - 1] : 0;
    __syncthreads();
    int gid = blockIdx.x * 256 + tid;
    if (gid < NN) {
        int o = tscan[gid] + base;
        offs[gid] = o;
        cursor[gid] = o;
    }
    if (gid == 0) offs[NN] = NE;
}

__global__ void k_scatter(const int* __restrict__ ei, int* __restrict__ cursor,
                          u16* __restrict__ ssrc) {
    int gid = blockIdx.x * blockDim.x + threadIdx.x;
    if (gid < NE) {
        int c = ei[NE + gid];
        int pos = atomicAdd(&cursor[c], 1);
        ssrc[pos] = (u16)ei[gid];
    }
}

// ---------------- fused input projection + layer-0 P/Q ----------------
__global__ __launch_bounds__(256)
void k_inputpq(const float* __restrict__ x, const float* __restrict__ iw,
               const float* __restrict__ ib,
               const bf16_t* __restrict__ w1t, const float* __restrict__ b1,
               bf16_t* __restrict__ h, bf16_t* __restrict__ P, bf16_t* __restrict__ Q) {
    const int lane = threadIdx.x & 63;
    const int g = lane >> 4;
    const int m16 = lane & 15;
    const int wid = (blockIdx.x * blockDim.x + threadIdx.x) >> 6;
    const int nw = (gridDim.x * blockDim.x) >> 6;

    bf16x8 wtop[2][4], wbot[2][4];
    #pragma unroll
    for (int s = 0; s < 2; ++s)
        #pragma unroll
        for (int nt = 0; nt < 4; ++nt) {
            wtop[s][nt] = load_frag(w1t + (16 * nt + m16) * 128 + 32 * s + 4 * g);
            wbot[s][nt] = load_frag(w1t + (16 * nt + m16) * 128 + 64 + 32 * s + 4 * g);
        }
    float b1f[4][4];
    #pragma unroll
    for (int nt = 0; nt < 4; ++nt)
        #pragma unroll
        for (int r = 0; r < 4; ++r) b1f[nt][r] = b1[16 * nt + 4 * g + r];

    float wcol[3][2][8], bcol[2][8];
    #pragma unroll
    for (int s = 0; s < 2; ++s)
        #pragma unroll
        for (int j = 0; j < 8; ++j) {
            int f = 32 * s + 4 * g + (j < 4 ? j : 16 + j - 4);
            bcol[s][j] = ib[f];
            #pragma unroll
            for (int i = 0; i < 3; ++i) wcol[i][s][j] = iw[i * 64 + f];
        }

    const int ntiles = NN / 16;
    for (int t = wid; t < ntiles; t += nw) {
        const int node = t * 16 + m16;
        float x0 = x[node * 3 + 0], x1 = x[node * 3 + 1], x2 = x[node * 3 + 2];
        bf16x8 hb[2];
        #pragma unroll
        for (int s = 0; s < 2; ++s)
            #pragma unroll
            for (int j = 0; j < 8; ++j) {
                float hf = bcol[s][j] + x0 * wcol[0][s][j] + x1 * wcol[1][s][j]
                         + x2 * wcol[2][s][j];
                hb[s][j] = (bf16_t)hf;
            }
        #pragma unroll
        for (int s = 0; s < 2; ++s) {
            bf16x4 lo, hi;
            #pragma unroll
            for (int j = 0; j < 4; ++j) { lo[j] = hb[s][j]; hi[j] = hb[s][4 + j]; }
            *(bf16x4*)(h + node * 64 + 32 * s + 4 * g) = lo;
            *(bf16x4*)(h + node * 64 + 32 * s + 16 + 4 * g) = hi;
        }

        f32x4 accP[4], accQ[4];
        #pragma unroll
        for (int nt = 0; nt < 4; ++nt) {
            accP[nt] = (f32x4){0.f, 0.f, 0.f, 0.f};
            accQ[nt] = (f32x4){0.f, 0.f, 0.f, 0.f};
        }
        #pragma unroll
        for (int s = 0; s < 2; ++s)
            #pragma unroll
            for (int nt = 0; nt < 4; ++nt) {
                accP[nt] = __builtin_amdgcn_mfma_f32_16x16x32_bf16(wtop[s][nt], hb[s], accP[nt], 0, 0, 0);
                accQ[nt] = __builtin_amdgcn_mfma_f32_16x16x32_bf16(wbot[s][nt], hb[s], accQ[nt], 0, 0, 0);
            }
        #pragma unroll
        for (int nt = 0; nt < 4; ++nt) {
            bf16x4 vp, vq;
            #pragma unroll
            for (int r = 0; r < 4; ++r) {
                vp[r] = (bf16_t)accP[nt][r];
                vq[r] = (bf16_t)(accQ[nt][r] + b1f[nt][r]);
            }
            *(bf16x4*)(P + node * 64 + 16 * nt + 4 * g) = vp;
            *(bf16x4*)(Q + node * 64 + 16 * nt + 4 * g) = vq;
        }
    }
}

// ---------------- per-layer edge phase, split-2, u16 sources ----------------
__global__ void k_edge(const bf16_t* __restrict__ P, const bf16_t* __restrict__ Q,
                       const u16* __restrict__ ssrc, const int* __restrict__ offs,
                       bf16_t* __restrict__ S, bf16_t* __restrict__ S2) {
    int gid = blockIdx.x * blockDim.x + threadIdx.x;
    int oct = gid >> 3, f8 = gid & 7;
    int node = oct >> 1, half = oct & 1;
    if (node >= NN) return;
    bf16x8 qv = *(const bf16x8*)(Q + node * 64 + f8 * 8);
    float qf[8], a[8];
    #pragma unroll
    for (int r = 0; r < 8; ++r) { qf[r] = (float)qv[r]; a[r] = 0.f; }
    const int b0 = offs[node], e0 = offs[node + 1];
    const int mid = b0 + ((e0 - b0 + 1) >> 1);
    const int beg = half ? mid : b0;
    const int end = half ? e0 : mid;
    int p = beg;
    const int n4 = beg + ((end - beg) & ~3);
    for (; p < n4; p += 4) {
        int s0 = ssrc[p], s1 = ssrc[p + 1], s2 = ssrc[p + 2], s3 = ssrc[p + 3];
        bf16x8 v0 = *(const bf16x8*)(P + s0 * 64 + f8 * 8);
        bf16x8 v1 = *(const bf16x8*)(P + s1 * 64 + f8 * 8);
        bf16x8 v2 = *(const bf16x8*)(P + s2 * 64 + f8 * 8);
        bf16x8 v3 = *(const bf16x8*)(P + s3 * 64 + f8 * 8);
        #pragma unroll
        for (int r = 0; r < 8; ++r) {
            float x0 = (float)v0[r] + qf[r];
            float x1 = (float)v1[r] + qf[r];
            float x2 = (float)v2[r] + qf[r];
            float x3 = (float)v3[r] + qf[r];
            a[r] += (x0 > 0.f ? x0 : 0.f) + (x1 > 0.f ? x1 : 0.f)
                  + (x2 > 0.f ? x2 : 0.f) + (x3 > 0.f ? x3 : 0.f);
        }
    }
    for (; p < end; ++p) {
        int s = ssrc[p];
        bf16x8 v = *(const bf16x8*)(P + s * 64 + f8 * 8);
        #pragma unroll
        for (int r = 0; r < 8; ++r) {
            float x = (float)v[r] + qf[r];
            a[r] += x > 0.f ? x : 0.f;
        }
    }
    bf16x8 sv;
    #pragma unroll
    for (int r = 0; r < 8; ++r) sv[r] = (bf16_t)a[r];
    bf16_t* dst = half ? S2 : S;
    *(bf16x8*)(dst + node * 64 + f8 * 8) = sv;
}

// ---------------- fused update + next-layer P/Q ----------------
__global__ __launch_bounds__(256)
void k_updpq(const bf16_t* __restrict__ h, const bf16_t* __restrict__ S,
             const bf16_t* __restrict__ S2, const int* __restrict__ deg,
             const bf16_t* __restrict__ u1t, const bf16_t* __restrict__ w2u,
             const bf16_t* __restrict__ u2t,
             const float* __restrict__ ub1, const float* __restrict__ cvec,
             const float* __restrict__ ub2,
             const bf16_t* __restrict__ w1tn, const float* __restrict__ b1n,
             bf16_t* __restrict__ hn, bf16_t* __restrict__ P, bf16_t* __restrict__ Q) {
    const int lane = threadIdx.x & 63;
    const int g = lane >> 4;
    const int m16 = lane & 15;
    const int wid = (blockIdx.x * blockDim.x + threadIdx.x) >> 6;
    const int nw = (gridDim.x * blockDim.x) >> 6;

    bf16x8 u1f[2][4], w2f[2][4], u2f[2][4], wtop[2][4], wbot[2][4];
    #pragma unroll
    for (int s = 0; s < 2; ++s)
        #pragma unroll
        for (int nt = 0; nt < 4; ++nt) {
            u1f[s][nt] = load_frag(u1t + (16 * nt + m16) * 64 + 32 * s + 4 * g);
            w2f[s][nt] = load_frag(w2u + (16 * nt + m16) * 64 + 32 * s + 4 * g);
            u2f[s][nt] = load_frag(u2t + (16 * nt + m16) * 64 + 32 * s + 4 * g);
            wtop[s][nt] = load_frag(w1tn + (16 * nt + m16) * 128 + 32 * s + 4 * g);
            wbot[s][nt] = load_frag(w1tn + (16 * nt + m16) * 128 + 64 + 32 * s + 4 * g);
        }
    float b1f[4][4], cf[4][4], b2f[4][4], b1nf[4][4];
    #pragma unroll
    for (int nt = 0; nt < 4; ++nt)
        #pragma unroll
        for (int r = 0; r < 4; ++r) {
            b1f[nt][r] = ub1[16 * nt + 4 * g + r];
            cf[nt][r] = cvec[16 * nt + 4 * g + r];
            b2f[nt][r] = ub2[16 * nt + 4 * g + r];
            b1nf[nt][r] = b1n[16 * nt + 4 * g + r];
        }

    const int ntiles = NN / 16;
    for (int t = wid; t < ntiles; t += nw) {
        const int node = t * 16 + m16;
        bf16x8 hfr[2], sfr[2];
        hfr[0] = load_frag(h + node * 64 + 4 * g);
        hfr[1] = load_frag(h + node * 64 + 4 * g + 32);
        sfr[0] = load_frag2(S + node * 64 + 4 * g, S2 + node * 64 + 4 * g);
        sfr[1] = load_frag2(S + node * 64 + 4 * g + 32, S2 + node * 64 + 4 * g + 32);
        float dv = (float)deg[node];

        f32x4 acc1[4];
        #pragma unroll
        for (int nt = 0; nt < 4; ++nt) acc1[nt] = (f32x4){0.f, 0.f, 0.f, 0.f};
        #pragma unroll
        for (int s = 0; s < 2; ++s)
            #pragma unroll
            for (int nt = 0; nt < 4; ++nt) {
                acc1[nt] = __builtin_amdgcn_mfma_f32_16x16x32_bf16(u1f[s][nt], hfr[s], acc1[nt], 0, 0, 0);
                acc1[nt] = __builtin_amdgcn_mfma_f32_16x16x32_bf16(w2f[s][nt], sfr[s], acc1[nt], 0, 0, 0);
            }

        bf16x8 hb[2];
        #pragma unroll
        for (int s = 0; s < 2; ++s) {
            bf16x8 f;
            #pragma unroll
            for (int half = 0; half < 2; ++half) {
                const int nt = 2 * s + half;
                #pragma unroll
                for (int r = 0; r < 4; ++r) {
                    float v = acc1[nt][r] + b1f[nt][r] + dv * cf[nt][r];
                    v = v > 0.f ? v : 0.f;
                    f[4 * half + r] = (bf16_t)v;
                }
            }
            hb[s] = f;
        }

        f32x4 acc2[4];
        #pragma unroll
        for (int nt = 0; nt < 4; ++nt) acc2[nt] = (f32x4){0.f, 0.f, 0.f, 0.f};
        #pragma unroll
        for (int s = 0; s < 2; ++s)
            #pragma unroll
            for (int nt = 0; nt < 4; ++nt)
                acc2[nt] = __builtin_amdgcn_mfma_f32_16x16x32_bf16(u2f[s][nt], hb[s], acc2[nt], 0, 0, 0);

        bf16x8 hb2[2];
        #pragma unroll
        for (int s = 0; s < 2; ++s) {
            bf16x8 f;
            #pragma unroll
            for (int half = 0; half < 2; ++half) {
                const int nt = 2 * s + half;
                #pragma unroll
                for (int r = 0; r < 4; ++r) {
                    float v = acc2[nt][r] + b2f[nt][r];
                    f[4 * half + r] = (bf16_t)(v > 0.f ? v : 0.f);
                }
            }
            hb2[s] = f;
        }
        #pragma unroll
        for (int s = 0; s < 2; ++s) {
            bf16x4 lo, hi;
            #pragma unroll
            for (int j = 0; j < 4; ++j) { lo[j] = hb2[s][j]; hi[j] = hb2[s][4 + j]; }
            *(bf16x4*)(hn + node * 64 + 32 * s + 4 * g) = lo;
            *(bf16x4*)(hn + node * 64 + 32 * s + 16 + 4 * g) = hi;
        }

        f32x4 accP[4], accQ[4];
        #pragma unroll
        for (int nt = 0; nt < 4; ++nt) {
            accP[nt] = (f32x4){0.f, 0.f, 0.f, 0.f};
            accQ[nt] = (f32x4){0.f, 0.f, 0.f, 0.f};
        }
        #pragma unroll
        for (int s = 0; s < 2; ++s)
            #pragma unroll
            for (int nt = 0; nt < 4; ++nt) {
                accP[nt] = __builtin_amdgcn_mfma_f32_16x16x32_bf16(wtop[s][nt], hb2[s], accP[nt], 0, 0, 0);
                accQ[nt] = __builtin_amdgcn_mfma_f32_16x16x32_bf16(wbot[s][nt], hb2[s], accQ[nt], 0, 0, 0);
            }
        #pragma unroll
        for (int nt = 0; nt < 4; ++nt) {
            bf16x4 vp, vq;
            #pragma unroll
            for (int r = 0; r < 4; ++r) {
                vp[r] = (bf16_t)accP[nt][r];
                vq[r] = (bf16_t)(accQ[nt][r] + b1nf[nt][r]);
            }
            *(bf16x4*)(P + node * 64 + 16 * nt + 4 * g) = vp;
            *(bf16x4*)(Q + node * 64 + 16 * nt + 4 * g) = vq;
        }
    }
}

// ---------------- plain update (last layer) ----------------
__global__ void k_upd(const bf16_t* __restrict__ h, const bf16_t* __restrict__ S,
                      const bf16_t* __restrict__ S2, const int* __restrict__ deg,
                      const bf16_t* __restrict__ u1t, const bf16_t* __restrict__ w2u,
                      const bf16_t* __restrict__ u2t,
                      const float* __restrict__ ub1, const float* __restrict__ cvec,
                      const float* __restrict__ ub2, bf16_t* __restrict__ hn) {
    const int lane = threadIdx.x & 63;
    const int g = lane >> 4;
    const int m16 = lane & 15;
    const int wid = (blockIdx.x * blockDim.x + threadIdx.x) >> 6;
    const int nw = (gridDim.x * blockDim.x) >> 6;

    bf16x8 u1f[2][4], w2f[2][4], u2f[2][4];
    #pragma unroll
    for (int s = 0; s < 2; ++s)
        #pragma unroll
        for (int nt = 0; nt < 4; ++nt) {
            u1f[s][nt] = load_frag(u1t + (16 * nt + m16) * 64 + 32 * s + 4 * g);
            w2f[s][nt] = load_frag(w2u + (16 * nt + m16) * 64 + 32 * s + 4 * g);
            u2f[s][nt] = load_frag(u2t + (16 * nt + m16) * 64 + 32 * s + 4 * g);
        }
    float b1f[4][4], cf[4][4], b2f[4][4];
    #pragma unroll
    for (int nt = 0; nt < 4; ++nt)
        #pragma unroll
        for (int r = 0; r < 4; ++r) {
            b1f[nt][r] = ub1[16 * nt + 4 * g + r];
            cf[nt][r] = cvec[16 * nt + 4 * g + r];
            b2f[nt][r] = ub2[16 * nt + 4 * g + r];
        }

    const int ntiles = NN / 16;
    for (int t = wid; t < ntiles; t += nw) {
        const int node = t * 16 + m16;
        bf16x8 hfr[2], sfr[2];
        hfr[0] = load_frag(h + node * 64 + 4 * g);
        hfr[1] = load_frag(h + node * 64 + 4 * g + 32);
        sfr[0] = load_frag2(S + node * 64 + 4 * g, S2 + node * 64 + 4 * g);
        sfr[1] = load_frag2(S + node * 64 + 4 * g + 32, S2 + node * 64 + 4 * g + 32);
        float dv = (float)deg[node];

        f32x4 acc1[4];
        #pragma unroll
        for (int nt = 0; nt < 4; ++nt) acc1[nt] = (f32x4){0.f, 0.f, 0.f, 0.f};
        #pragma unroll
        for (int s = 0; s < 2; ++s)
            #pragma unroll
            for (int nt = 0; nt < 4; ++nt) {
                acc1[nt] = __builtin_amdgcn_mfma_f32_16x16x32_bf16(u1f[s][nt], hfr[s], acc1[nt], 0, 0, 0);
                acc1[nt] = __builtin_amdgcn_mfma_f32_16x16x32_bf16(w2f[s][nt], sfr[s], acc1[nt], 0, 0, 0);
            }

        bf16x8 hb[2];
        #pragma unroll
        for (int s = 0; s < 2; ++s) {
            bf16x8 f;
            #pragma unroll
            for (int half = 0; half < 2; ++half) {
                const int nt = 2 * s + half;
                #pragma unroll
                for (int r = 0; r < 4; ++r) {
                    float v = acc1[nt][r] + b1f[nt][r] + dv * cf[nt][r];
                    v = v > 0.f ? v : 0.f;
                    f[4 * half + r] = (bf16_t)v;
                }
            }
            hb[s] = f;
        }

        f32x4 acc2[4];
        #pragma unroll
        for (int nt = 0; nt < 4; ++nt) acc2[nt] = (f32x4){0.f, 0.f, 0.f, 0.f};
        #pragma unroll
        for (int s = 0; s < 2; ++s)
            #pragma unroll
            for (int nt = 0; nt < 4; ++nt)
                acc2[nt] = __builtin_amdgcn_mfma_f32_16x16x32_bf16(u2f[s][nt], hb[s], acc2[nt], 0, 0, 0);

        #pragma unroll
        for (int nt = 0; nt < 4; ++nt) {
            bf16x4 v4;
            #pragma unroll
            for (int r = 0; r < 4; ++r) {
                float v = acc2[nt][r] + b2f[nt][r];
                v4[r] = (bf16_t)(v > 0.f ? v : 0.f);
            }
            *(bf16x4*)(hn + node * 64 + 16 * nt + 4 * g) = v4;
        }
    }
}

// ---------------- output projection (MFMA, split hi/lo weights) ----------------
__global__ __launch_bounds__(256)
void k_outm(const bf16_t* __restrict__ whi_t, const bf16_t* __restrict__ wlo_t,
            const bf16_t* __restrict__ h, const float* __restrict__ b,
            float* __restrict__ out) {
    const int lane = threadIdx.x & 63;
    const int g = lane >> 4;
    const int m16 = lane & 15;
    const int wid = (blockIdx.x * blockDim.x + threadIdx.x) >> 6;
    const int nw = (gridDim.x * blockDim.x) >> 6;

    bf16x8 whi[2][8], wlo[2][8];
    #pragma unroll
    for (int s = 0; s < 2; ++s)
        #pragma unroll
        for (int nt = 0; nt < 8; ++nt) {
            whi[s][nt] = load_frag(whi_t + (16 * nt + m16) * 64 + 32 * s + 4 * g);
            wlo[s][nt] = load_frag(wlo_t + (16 * nt + m16) * 64 + 32 * s + 4 * g);
        }
    f32x4 bfv[8];
    #pragma unroll
    for (int nt = 0; nt < 8; ++nt)
        #pragma unroll
        for (int r = 0; r < 4; ++r) bfv[nt][r] = b[16 * nt + 4 * g + r];

    const int ntiles = NN / 16;
    for (int t = wid; t < ntiles; t += nw) {
        const int node = t * 16 + m16;
        bf16x8 hfr[2];
        hfr[0] = load_frag(h + node * 64 + 4 * g);
        hfr[1] = load_frag(h + node * 64 + 4 * g + 32);

        f32x4 acc[8];
        #pragma unroll
        for (int nt = 0; nt < 8; ++nt) acc[nt] = (f32x4){0.f, 0.f, 0.f, 0.f};
        #pragma unroll
        for (int s = 0; s < 2; ++s)
            #pragma unroll
            for (int nt = 0; nt < 8; ++nt) {
                acc[nt] = __builtin_amdgcn_mfma_f32_16x16x32_bf16(whi[s][nt], hfr[s], acc[nt], 0, 0, 0);
                acc[nt] = __builtin_amdgcn_mfma_f32_16x16x32_bf16(wlo[s][nt], hfr[s], acc[nt], 0, 0, 0);
            }
        #pragma unroll
        for (int nt = 0; nt < 8; ++nt)
            *(f32x4*)(out + node * 128 + 16 * nt + 4 * g) = acc[nt] + bfv[nt];
    }
}

extern "C" void kernel_launch(void* const* d_in, const int* in_sizes, int n_in,
                              void* d_out, int out_size, void* d_ws, size_t ws_size,
                              hipStream_t stream) {
    const float* x      = (const float*)d_in[0];
    const int*   ei     = (const int*)d_in[1];
    const float* in_w   = (const float*)d_in[2];
    const float* in_b   = (const float*)d_in[3];
    const float* msg_w1 = (const float*)d_in[4];
    const float* msg_b1 = (const float*)d_in[5];
    const float* msg_w2 = (const float*)d_in[6];
    const float* msg_b2 = (const float*)d_in[7];
    const float* upd_w1 = (const float*)d_in[8];
    const float* upd_b1 = (const float*)d_in[9];
    const float* upd_w2 = (const float*)d_in[10];
    const float* upd_b2 = (const float*)d_in[11];
    const float* out_w  = (const float*)d_in[12];
    const float* out_b  = (const float*)d_in[13];
    float* out = (float*)d_out;

    char* ws = (char*)d_ws;
    bf16_t* h_a    = (bf16_t*)(ws);
    bf16_t* h_b    = (bf16_t*)(ws + 6400000);
    bf16_t* P      = (bf16_t*)(ws + 12800000);
    bf16_t* Q      = (bf16_t*)(ws + 19200000);
    bf16_t* S      = (bf16_t*)(ws + 25600000);
    u16*    ssrc   = (u16*)   (ws + 32000000);   // 1.6 MB (u16)
    int*    deg    = (int*)   (ws + 35200000);
    int*    offs   = (int*)   (ws + 35400000);
    int*    cursor = (int*)   (ws + 35600128);
    int*    tscan  = (int*)   (ws + 35800192);
    int*    part   = (int*)   (ws + 36000256);
    bf16_t* w1t    = (bf16_t*)(ws + 36002304);
    bf16_t* u1t    = (bf16_t*)(ws + 36051456);
    bf16_t* u2t    = (bf16_t*)(ws + 36076032);
    bf16_t* w2u    = (bf16_t*)(ws + 36100608);
    float*  cvec   = (float*) (ws + 36125184);
    bf16_t* whi    = (bf16_t*)(ws + 36126208);   // 16 KB
    bf16_t* wlo    = (bf16_t*)(ws + 36142592);   // 16 KB
    bf16_t* S2     = (bf16_t*)(ws + 36160000);   // 6.4 MB

    // fused weight prep + deg zeroing
    k_prepall<<<96, 256, 0, stream>>>(msg_w1, upd_w1, upd_w2, msg_w2, msg_b2, out_w,
                                      w1t, u1t, u2t, w2u, cvec, whi, wlo, deg);

    // counting sort of edges by destination
    k_hist<<<(NE + 255) / 256, 256, 0, stream>>>(ei, deg);
    k_scan1<<<SCAN_BLKS, 256, 0, stream>>>(deg, tscan, part);
    k_scan23<<<SCAN_BLKS, 256, 0, stream>>>(tscan, part, offs, cursor);
    k_scatter<<<(NE + 255) / 256, 256, 0, stream>>>(ei, cursor, ssrc);

    // fused input projection + layer-0 P/Q
    k_inputpq<<<512, 256, 0, stream>>>(x, in_w, in_b, w1t, msg_b1, h_a, P, Q);

    bf16_t* hc = h_a;
    bf16_t* hn = h_b;
    for (int l = 0; l < 3; ++l) {
        k_edge<<<(NN * 16 + 255) / 256, 256, 0, stream>>>(P, Q, ssrc, offs, S, S2);
        if (l < 2) {
            k_updpq<<<512, 256, 0, stream>>>(hc, S, S2, deg,
                u1t + l * 4096, w2u + l * 4096, u2t + l * 4096,
                upd_b1 + l * 64, cvec + l * 64, upd_b2 + l * 64,
                w1t + (l + 1) * 8192, msg_b1 + (l + 1) * 64,
                hn, P, Q);
        } else {
            k_upd<<<512, 256, 0, stream>>>(hc, S, S2, deg,
                u1t + l * 4096, w2u + l * 4096, u2t + l * 4096,
                upd_b1 + l * 64, cvec + l * 64, upd_b2 + l * 64, hn);
        }
        bf16_t* tmp = hc; hc = hn; hn = tmp;
    }
    k_outm<<<640, 256, 0, stream>>>(whi, wlo, hc, out_b, out);
}